// Round 9
// baseline (940.839 us; speedup 1.0000x reference)
//
#include <hip/hip_runtime.h>

#define NB 16384
#define ND 768
#define NF 8192
#define CMAX 512        // candidate list cap per row
#define AMAX 128        // ambiguous cap per row (expect ~13)
#define MARG 0.07f      // classification margin (>= 2x bf16-GEMM act error bound)
#define THETA0 2.0f     // GEMM-side candidate threshold (bf16-exact)
#define THETA0_BITS 0x4000u

typedef __attribute__((ext_vector_type(8))) short bf16x8;
typedef __attribute__((ext_vector_type(4))) float f32x4;
typedef __attribute__((ext_vector_type(4))) unsigned int u32x4;
typedef __attribute__((ext_vector_type(2))) float f32x2;

__device__ inline unsigned short f2bf(float f) {
  unsigned u = __float_as_uint(f);
  unsigned r = (u + 0x7FFFu + ((u >> 16) & 1u)) >> 16;
  return (unsigned short)r;
}
__device__ inline float bfbits2f(unsigned u16) { return __uint_as_float(u16 << 16); }

// ---------------------------------------------------------------------------
__global__ __launch_bounds__(256) void zerocnt_k(unsigned* __restrict__ gcnt) {
  gcnt[blockIdx.x * 256 + threadIdx.x] = 0u;
}

// ---------------------------------------------------------------------------
__global__ __launch_bounds__(256) void cvt_bf16_k(const float* __restrict__ in,
                                                  unsigned short* __restrict__ out) {
  size_t t = (size_t)blockIdx.x * 256 + threadIdx.x;
  const float4* i4 = (const float4*)in;
  float4 a = i4[t * 2], b = i4[t * 2 + 1];
  ushort4 lo = make_ushort4(f2bf(a.x), f2bf(a.y), f2bf(a.z), f2bf(a.w));
  ushort4 hi = make_ushort4(f2bf(b.x), f2bf(b.y), f2bf(b.z), f2bf(b.w));
  ((ushort4*)out)[t * 2] = lo;
  ((ushort4*)out)[t * 2 + 1] = hi;
}

// ---------------------------------------------------------------------------
__global__ __launch_bounds__(256) void beta_k(const float* __restrict__ W_enc,
                                              const float* __restrict__ b_enc,
                                              const float* __restrict__ dec_bias,
                                              float* __restrict__ beta) {
  int f = blockIdx.x * 4 + (threadIdx.x >> 6);
  int lane = threadIdx.x & 63;
  const float* wr = W_enc + (size_t)f * ND;
  float s = 0.f;
  for (int d = lane; d < ND; d += 64) s += dec_bias[d] * wr[d];
  for (int off = 32; off; off >>= 1) s += __shfl_down(s, off);
  if (lane == 0) beta[f] = b_enc[f] - s;
}

// ---------------------------------------------------------------------------
__global__ __launch_bounds__(256) void transpose_bf_k(const float* __restrict__ in,
                                                      unsigned short* __restrict__ out) {
  __shared__ float tile[32][33];
  int lx = threadIdx.x & 31;
  int ty = threadIdx.x >> 5;
  int x = blockIdx.x * 32 + lx;  // f
  for (int j = ty; j < 32; j += 8) {
    int y = blockIdx.y * 32 + j;  // d
    tile[j][lx] = in[(size_t)y * NF + x];
  }
  __syncthreads();
  int xo = blockIdx.y * 32 + lx;  // d
  for (int j = ty; j < 32; j += 8) {
    int yo = blockIdx.x * 32 + j;  // f
    out[(size_t)yo * ND + xo] = f2bf(tile[lx][j]);
  }
}

// ---------------------------------------------------------------------------
// bf16 MFMA GEMM v4: round-8 structure + fused candidate append (v>=THETA0)
// into per-row global lists. acts + tmax still written (fallback insurance).
__global__ __launch_bounds__(256) void enc_gemm_bf16(
    const unsigned short* __restrict__ Xb, const unsigned short* __restrict__ Wb,
    const float* __restrict__ beta, unsigned short* __restrict__ acts,
    unsigned short* __restrict__ tmax,
    unsigned* __restrict__ gcnt, unsigned* __restrict__ glist) {
  __shared__ __align__(1024) unsigned short SL[2][128 * 64];
  unsigned short* As = SL[0];
  unsigned short* Bs = SL[1];
  const int tid = threadIdx.x;
  const int wave = tid >> 6, lane = tid & 63;
  const int wm = wave >> 1, wn = wave & 1;

  const int orig = blockIdx.y * gridDim.x + blockIdx.x;  // 0..8191
  const int xcd = orig & 7;
  const int local = orig >> 3;          // 0..1023
  const int tcol = local >> 4;          // 0..63
  const int trow = (xcd << 4) + (local & 15);
  const int brow = trow << 7;
  const int bcol = tcol << 7;

  f32x4 acc[4][4] = {};

  const int srow = tid >> 3;                                   // 0..31
  const int scol = (((tid & 7) ^ ((tid >> 3) & 7)) << 3);      // pre-swizzled source chunk
  const unsigned short* gA = Xb + (size_t)(brow + srow) * ND + scol;
  const unsigned short* gB = Wb + (size_t)(bcol + srow) * ND + scol;

  for (int kt = 0; kt < ND; kt += 64) {
#pragma unroll
    for (int i = 0; i < 4; ++i) {
      __builtin_amdgcn_global_load_lds(
          (const __attribute__((address_space(1))) void*)(gA + (size_t)(i * 32) * ND + kt),
          (__attribute__((address_space(3))) void*)(As + (i * 32 + wave * 8) * 64), 16, 0, 0);
      __builtin_amdgcn_global_load_lds(
          (const __attribute__((address_space(1))) void*)(gB + (size_t)(i * 32) * ND + kt),
          (__attribute__((address_space(3))) void*)(Bs + (i * 32 + wave * 8) * 64), 16, 0, 0);
    }
    __syncthreads();
#pragma unroll
    for (int kk = 0; kk < 64; kk += 32) {
      const int chunk = (kk + ((lane >> 4) << 3)) >> 3;  // 0..7 (16B units)
      const int rA = (wm << 6) + (lane & 15);
      const int rB = (wn << 6) + (lane & 15);
      const int sw = chunk ^ (lane & 7);  // row&7 == lane&7 for all frag rows
      bf16x8 a[4], bvv[4];
#pragma unroll
      for (int m = 0; m < 4; ++m)
        a[m] = *(const bf16x8*)&As[(rA + (m << 4)) * 64 + (sw << 3)];
#pragma unroll
      for (int n = 0; n < 4; ++n)
        bvv[n] = *(const bf16x8*)&Bs[(rB + (n << 4)) * 64 + (sw << 3)];
#pragma unroll
      for (int m = 0; m < 4; ++m)
#pragma unroll
        for (int n = 0; n < 4; ++n)
          acc[m][n] = __builtin_amdgcn_mfma_f32_16x16x32_bf16(a[m], bvv[n], acc[m][n], 0, 0, 0);
    }
    __syncthreads();
  }

  // ---- epilogue: acc -> LDS (swizzled 16B slots) + candidate append
  unsigned short* S = (unsigned short*)SL;  // 128 x 128 shorts (32 KB)
#pragma unroll
  for (int n = 0; n < 4; ++n) {
    float bet = beta[bcol + (wn << 6) + (n << 4) + (lane & 15)];
#pragma unroll
    for (int m = 0; m < 4; ++m) {
#pragma unroll
      for (int r = 0; r < 4; ++r) {
        int row_l = (wm << 6) + (m << 4) + ((lane >> 4) << 2) + r;
        int col_l = (wn << 6) + (n << 4) + (lane & 15);
        float v = fmaxf(acc[m][n][r] + bet, 0.f);
        unsigned short ub = f2bf(v);
        int slot = (col_l >> 3) ^ (row_l & 7);
        S[row_l * 128 + (slot << 3) + (col_l & 7)] = ub;
        if (ub >= (unsigned short)THETA0_BITS) {
          unsigned p = atomicAdd(&gcnt[brow + row_l], 1u);
          if (p < CMAX)
            glist[(size_t)(brow + row_l) * CMAX + p] =
                ((unsigned)ub << 16) | (unsigned)(bcol + col_l);
        }
      }
    }
  }
  __syncthreads();
  // coalesced acts stores + per-(row,tile) max
#pragma unroll
  for (int i = 0; i < 8; ++i) {
    int row_l = (tid >> 4) + (i << 4);
    int slot = tid & 15;
    u32x4 d = *(const u32x4*)&S[row_l * 128 + (slot << 3)];
    unsigned mx = 0;
#pragma unroll
    for (int q = 0; q < 4; ++q) {
      unsigned lo = d[q] & 0xFFFFu, hi = d[q] >> 16;
      if (lo > mx) mx = lo;
      if (hi > mx) mx = hi;
    }
#pragma unroll
    for (int off = 1; off < 16; off <<= 1) {
      unsigned o = __shfl_xor(mx, off);
      if (o > mx) mx = o;
    }
    int chunk = slot ^ (row_l & 7);
    __builtin_nontemporal_store(
        d, (u32x4*)&acts[(size_t)(brow + row_l) * NF + bcol + (chunk << 3)]);
    if (slot == 0) tmax[(size_t)(brow + row_l) * 64 + tcol] = (unsigned short)mx;
  }
}

// ---------------------------------------------------------------------------
// ksel v4: wave-per-row. Fast path: GEMM-built candidate list (no acts read).
// Validity (provable): raw<=CMAX (list complete for v>=THETA0), cnt>=k
// (=> tau_list == true bf16 tau), tau >= THETA0+MARG (=> ambiguous band in
// list). Any wave invalid -> whole block runs the round-8 streaming path.
__global__ __launch_bounds__(256, 6) void ksel_k(
    const unsigned short* __restrict__ acts, const unsigned short* __restrict__ tmax,
    const unsigned* __restrict__ gcnt, const unsigned* __restrict__ glist,
    const float* __restrict__ x, const float* __restrict__ W_enc,
    const float* __restrict__ beta, const unsigned short* __restrict__ WdecBf,
    const float* __restrict__ dec_bias, const int* __restrict__ kptr,
    float* __restrict__ out_rec, float* __restrict__ g_vals, int* __restrict__ g_idxs) {
  const int tid = threadIdx.x, wave = tid >> 6, lane = tid & 63;
  const int b = blockIdx.x * 4 + wave;
  int k = *kptr; k = k < 1 ? 1 : (k > 64 ? 64 : k);
  const unsigned kk = (unsigned)k;

  __shared__ int stile_s[4][64];
  __shared__ unsigned clist_s[4][CMAX];
  __shared__ unsigned long long aval_s[4][AMAX];
  __shared__ float selv_s[4][64];
  __shared__ int seli_s[4][64];
  __shared__ int ctrC_s[4], ctrW_s[4], ctrA_s[4];
  __shared__ int blkFb;

  int* stile = stile_s[wave];
  unsigned* clist = clist_s[wave];
  unsigned long long* aval = aval_s[wave];
  float* selv = selv_s[wave];
  int* seli = seli_s[wave];

  if (tid == 0) blkFb = 0;
  if (lane == 0) { ctrC_s[wave] = 0; ctrW_s[wave] = 0; ctrA_s[wave] = 0; }

  // ---- fast path: load GEMM-built list
  const int raw = (int)gcnt[b];
  int n = raw < CMAX ? raw : CMAX;
  for (int j = lane; j < n; j += 64) clist[j] = glist[(size_t)b * CMAX + j];
  __syncthreads();

  // tau via 15-probe bitwise binary search over the list
  unsigned ks[8];
#pragma unroll
  for (int ii = 0; ii < 8; ++ii) {
    int j = lane + (ii << 6);
    ks[ii] = (j < n) ? (clist[j] >> 16) : 0u;
  }
  unsigned T = 0;
  for (int bit = 14; bit >= 0; --bit) {
    unsigned probe = T | (1u << bit);
    int c = 0;
#pragma unroll
    for (int ii = 0; ii < 8; ++ii) c += (ks[ii] >= probe);
#pragma unroll
    for (int off = 32; off; off >>= 1) c += __shfl_xor(c, off);
    if (c >= (int)kk) T = probe;
  }
  float tauf = bfbits2f(T);

  bool valid = (raw <= CMAX) && (n >= k) && (tauf >= THETA0 + MARG);
  if (lane == 0 && !valid) atomicOr(&blkFb, 1);
  __syncthreads();

  if (blkFb) {
    // ---- fallback: round-8 streaming path (block-uniform)
    // inline Lthr: L = k-th largest tile max (provably <= tau)
    unsigned tm = tmax[(size_t)b * 64 + lane];
    unsigned T2 = 0;
    for (int bit = 14; bit >= 0; --bit) {
      unsigned probe = T2 | (1u << bit);
      int c = __popcll(__ballot(tm >= probe));
      if (c >= k) T2 = probe;
    }
    const float Lf = bfbits2f(T2) - MARG;
    if (lane == 0) ctrC_s[wave] = 0;
    // tile selection
    {
      bool sel = bfbits2f(tm) >= Lf;
      unsigned long long mask = __ballot(sel);
      int pos = __popcll(mask & ((1ull << lane) - 1ull));
      if (sel) stile[pos] = lane;
    }
    __syncthreads();
    const int nsel = __popcll(__ballot(bfbits2f(tm) >= Lf));
    const u32x4* row16 = (const u32x4*)(acts + (size_t)b * NF);
    for (int t = 0; t < nsel; t += 4) {
      int tt = t + (lane >> 4);
      if (tt < nsel) {
        int tile = stile[tt];
        u32x4 v = __builtin_nontemporal_load(&row16[tile * 16 + (lane & 15)]);
        int base = tile * 128 + (lane & 15) * 8;
#pragma unroll
        for (int q = 0; q < 4; ++q) {
#pragma unroll
          for (int h = 0; h < 2; ++h) {
            unsigned u = h ? (v[q] >> 16) : (v[q] & 0xFFFFu);
            if (bfbits2f(u) >= Lf) {
              int p = atomicAdd(&ctrC_s[wave], 1);
              if (p < CMAX) clist[p] = (u << 16) | (unsigned)(base + q * 2 + h);
            }
          }
        }
      }
    }
    __syncthreads();
    n = ctrC_s[wave]; if (n > CMAX) n = CMAX;
    // recompute tau over rebuilt list
#pragma unroll
    for (int ii = 0; ii < 8; ++ii) {
      int j = lane + (ii << 6);
      ks[ii] = (j < n) ? (clist[j] >> 16) : 0u;
    }
    T = 0;
    for (int bit = 14; bit >= 0; --bit) {
      unsigned probe = T | (1u << bit);
      int c = 0;
#pragma unroll
      for (int ii = 0; ii < 8; ++ii) c += (ks[ii] >= probe);
#pragma unroll
      for (int off = 32; off; off >>= 1) c += __shfl_xor(c, off);
      if (c >= (int)kk) T = probe;
    }
    tauf = bfbits2f(T);
  }

  const float thrW = tauf + MARG;
  const float thrA = tauf - MARG;

  // ---- classify: winners (bf16 value final) / ambiguous band
  for (int j = lane; j < n; j += 64) {
    unsigned e = clist[j];
    float v = bfbits2f(e >> 16);
    int idx = (int)(e & 0xFFFFu);
    if (v > thrW) {
      int p = atomicAdd(&ctrW_s[wave], 1);
      if (p < 63) { selv[p] = v; seli[p] = idx; }  // count(v > tau) <= k-1
    } else if (v >= thrA) {
      int p = atomicAdd(&ctrA_s[wave], 1);
      if (p < AMAX) aval[p] = (unsigned long long)(unsigned)idx;
    }
  }
  __syncthreads();
  int c = ctrW_s[wave]; if (c > 63) c = 63; if (c > k - 1) c = k - 1;
  int na = ctrA_s[wave]; if (na > AMAX) na = AMAX;

  // ---- exact fp32 dots for ambiguous (2-wide)
  float xr[12];
#pragma unroll
  for (int cc = 0; cc < 12; ++cc)
    xr[cc] = __builtin_nontemporal_load(&x[(size_t)b * ND + lane + 64 * cc]);
  for (int j = 0; j < na; j += 2) {
    int f0 = (int)(unsigned)aval[j];
    int f1 = (j + 1 < na) ? (int)(unsigned)aval[j + 1] : f0;
    const float* w0 = W_enc + (size_t)f0 * ND;
    const float* w1 = W_enc + (size_t)f1 * ND;
    float s0 = 0.f, s1 = 0.f;
#pragma unroll
    for (int cc = 0; cc < 12; ++cc) {
      s0 = fmaf(xr[cc], w0[lane + 64 * cc], s0);
      s1 = fmaf(xr[cc], w1[lane + 64 * cc], s1);
    }
#pragma unroll
    for (int off = 32; off; off >>= 1) {
      s0 += __shfl_xor(s0, off);
      s1 += __shfl_xor(s1, off);
    }
    if (lane == 0) {
      float v0 = fmaxf(s0 + beta[f0], 0.f);
      aval[j] = (((unsigned long long)__float_as_uint(v0)) << 13) | (unsigned)(8191 - f0);
      if (j + 1 < na) {
        float v1 = fmaxf(s1 + beta[f1], 0.f);
        aval[j + 1] = (((unsigned long long)__float_as_uint(v1)) << 13) | (unsigned)(8191 - f1);
      }
    }
  }
  __syncthreads();

  // ---- select top (k-c) ambiguous by (exact val desc, idx asc)
  {
    unsigned long long p0 = (lane < na) ? aval[lane] : 0ull;
    unsigned long long p1 = (lane + 64 < na) ? aval[lane + 64] : 0ull;
    int rounds = k - c; if (rounds < 0) rounds = 0;
    for (int r = 0; r < rounds; ++r) {
      unsigned long long m = p0 > p1 ? p0 : p1;
#pragma unroll
      for (int off = 32; off; off >>= 1) {
        unsigned long long o = __shfl_xor(m, off);
        if (o > m) m = o;
      }
      if (lane == 0) {
        if (m) { selv[c + r] = __uint_as_float((unsigned)(m >> 13)); seli[c + r] = 8191 - (int)(m & 0x1FFFull); }
        else   { selv[c + r] = 0.f; seli[c + r] = 0; }
      }
      if (p0 == m) p0 = 0;
      if (p1 == m) p1 = 0;
    }
  }
  __syncthreads();

  if (lane < k) {
    g_vals[(size_t)b * 64 + lane] = selv[lane];
    g_idxs[(size_t)b * 64 + lane] = seli[lane];
  }

  // ---- fused reconstruction (bf16 decoder gathers, cached)
  float acc[12];
#pragma unroll
  for (int cc = 0; cc < 6; ++cc) {
    float2 db = *(const float2*)&dec_bias[cc * 128 + lane * 2];
    acc[2 * cc] = db.x; acc[2 * cc + 1] = db.y;
  }
#define RECON_TERM(r)                                                          \
  {                                                                            \
    int f = seli[r]; float v = selv[r];                                        \
    const unsigned short* wd = WdecBf + (size_t)f * ND;                        \
    _Pragma("unroll")                                                          \
    for (int cc = 0; cc < 6; ++cc) {                                           \
      unsigned pr = *(const unsigned*)&wd[cc * 128 + lane * 2];                \
      acc[2 * cc] = fmaf(v, bfbits2f(pr & 0xFFFFu), acc[2 * cc]);              \
      acc[2 * cc + 1] = fmaf(v, bfbits2f(pr >> 16), acc[2 * cc + 1]);          \
    }                                                                          \
  }
  if (k == 32) {
#pragma unroll
    for (int r = 0; r < 32; ++r) RECON_TERM(r)
  } else {
    for (int r = 0; r < k; ++r) RECON_TERM(r)
  }
#pragma unroll
  for (int cc = 0; cc < 6; ++cc) {
    f32x2 st = {acc[2 * cc], acc[2 * cc + 1]};
    __builtin_nontemporal_store(st, (f32x2*)&out_rec[(size_t)b * ND + cc * 128 + lane * 2]);
  }
}

// ---------------------------------------------------------------------------
__global__ __launch_bounds__(256) void d2_sparse_k(
    const float* __restrict__ g_vals, const int* __restrict__ g_idxs,
    const int* __restrict__ kptr, float* __restrict__ out_sc) {
  const int b = blockIdx.x, tid = threadIdx.x;
  int k = *kptr; k = k < 1 ? 1 : (k > 64 ? 64 : k);
  __shared__ float row[NF];
  __shared__ float sv[64];
  __shared__ int si[64];
  if (tid < k) { sv[tid] = g_vals[(size_t)b * 64 + tid]; si[tid] = g_idxs[(size_t)b * 64 + tid]; }
  float4* r4 = (float4*)row;
#pragma unroll
  for (int i = 0; i < 8; ++i) r4[tid + 256 * i] = make_float4(0.f, 0.f, 0.f, 0.f);
  __syncthreads();
  if (tid < k) row[si[tid]] = sv[tid];
  __syncthreads();
  f32x4* o4 = (f32x4*)(out_sc + (size_t)b * NF);
  const f32x4* r4v = (const f32x4*)row;
#pragma unroll
  for (int i = 0; i < 8; ++i)
    __builtin_nontemporal_store(r4v[tid + 256 * i], &o4[tid + 256 * i]);
}

// ---------------------------------------------------------------------------
extern "C" void kernel_launch(void* const* d_in, const int* in_sizes, int n_in,
                              void* d_out, int out_size, void* d_ws, size_t ws_size,
                              hipStream_t stream) {
  const float* x        = (const float*)d_in[0];
  const float* W_enc    = (const float*)d_in[1];
  const float* b_enc    = (const float*)d_in[2];
  const float* W_dec    = (const float*)d_in[3];
  const float* dec_bias = (const float*)d_in[4];
  const int*   kptr     = (const int*)d_in[5];

  float* out_rec = (float*)d_out;
  float* out_sc  = (float*)d_out + (size_t)NB * ND;

  // scratch carved from the sparse-code output region (rewritten by d2 last)
  char* scb = (char*)out_sc;
  unsigned short* acts  = (unsigned short*)scb;                // 256 MB
  unsigned short* Xbf   = (unsigned short*)(scb + 268435456);  // 24 MB
  unsigned short* Wbf   = (unsigned short*)(scb + 293601280);  // 12 MB
  unsigned*       glist = (unsigned*)(scb + 306184192);        // 32 MB (16384*512*4)
  unsigned*       gcnt  = (unsigned*)(scb + 339738624);        // 64 KB

  char* ws = (char*)d_ws;
  unsigned short* WdecBf = (unsigned short*)ws;        // 12,582,912 B
  float* beta   = (float*)(ws + 12582912);             //     32,768 B
  float* g_vals = (float*)(ws + 12615680);             //  4,194,304 B
  int*   g_idxs = (int*)(ws + 16809984);               //  4,194,304 B
  unsigned short* tmax = (unsigned short*)(ws + 21004288); // 2,097,152 B

  zerocnt_k<<<64, 256, 0, stream>>>(gcnt);
  cvt_bf16_k<<<(NB * ND) / 2048, 256, 0, stream>>>(x, Xbf);
  cvt_bf16_k<<<(NF * ND) / 2048, 256, 0, stream>>>(W_enc, Wbf);
  beta_k<<<NF / 4, 256, 0, stream>>>(W_enc, b_enc, dec_bias, beta);
  transpose_bf_k<<<dim3(NF / 32, ND / 32), 256, 0, stream>>>(W_dec, WdecBf);
  enc_gemm_bf16<<<dim3(NF / 128, NB / 128), 256, 0, stream>>>(Xbf, Wbf, beta, acts,
                                                              tmax, gcnt, glist);
  ksel_k<<<NB / 4, 256, 0, stream>>>(acts, tmax, gcnt, glist, x, W_enc, beta, WdecBf,
                                     dec_bias, kptr, out_rec, g_vals, g_idxs);
  d2_sparse_k<<<NB, 256, 0, stream>>>(g_vals, g_idxs, kptr, out_sc);
}

// Round 10
// 676.704 us; speedup vs baseline: 1.3903x; 1.3903x over previous
//
#include <hip/hip_runtime.h>

#define NB 16384
#define ND 768
#define NF 8192
#define CMAX 512        // candidate list cap per row (64 tiles x 8 slots)
#define AMAX 128        // ambiguous cap per row (expect ~13)
#define MARG 0.07f      // classification margin (>= 2x bf16-GEMM act error bound)
#define THETA0 2.0f     // GEMM-side candidate threshold (bf16-exact)
#define THETA0_BITS 0x4000u

typedef __attribute__((ext_vector_type(8))) short bf16x8;
typedef __attribute__((ext_vector_type(4))) float f32x4;
typedef __attribute__((ext_vector_type(4))) unsigned int u32x4;
typedef __attribute__((ext_vector_type(2))) float f32x2;

__device__ inline unsigned short f2bf(float f) {
  unsigned u = __float_as_uint(f);
  unsigned r = (u + 0x7FFFu + ((u >> 16) & 1u)) >> 16;
  return (unsigned short)r;
}
__device__ inline float bfbits2f(unsigned u16) { return __uint_as_float(u16 << 16); }

// ---------------------------------------------------------------------------
__global__ __launch_bounds__(256) void cvt_bf16_k(const float* __restrict__ in,
                                                  unsigned short* __restrict__ out) {
  size_t t = (size_t)blockIdx.x * 256 + threadIdx.x;
  const float4* i4 = (const float4*)in;
  float4 a = i4[t * 2], b = i4[t * 2 + 1];
  ushort4 lo = make_ushort4(f2bf(a.x), f2bf(a.y), f2bf(a.z), f2bf(a.w));
  ushort4 hi = make_ushort4(f2bf(b.x), f2bf(b.y), f2bf(b.z), f2bf(b.w));
  ((ushort4*)out)[t * 2] = lo;
  ((ushort4*)out)[t * 2 + 1] = hi;
}

// ---------------------------------------------------------------------------
__global__ __launch_bounds__(256) void beta_k(const float* __restrict__ W_enc,
                                              const float* __restrict__ b_enc,
                                              const float* __restrict__ dec_bias,
                                              float* __restrict__ beta) {
  int f = blockIdx.x * 4 + (threadIdx.x >> 6);
  int lane = threadIdx.x & 63;
  const float* wr = W_enc + (size_t)f * ND;
  float s = 0.f;
  for (int d = lane; d < ND; d += 64) s += dec_bias[d] * wr[d];
  for (int off = 32; off; off >>= 1) s += __shfl_down(s, off);
  if (lane == 0) beta[f] = b_enc[f] - s;
}

// ---------------------------------------------------------------------------
__global__ __launch_bounds__(256) void transpose_bf_k(const float* __restrict__ in,
                                                      unsigned short* __restrict__ out) {
  __shared__ float tile[32][33];
  int lx = threadIdx.x & 31;
  int ty = threadIdx.x >> 5;
  int x = blockIdx.x * 32 + lx;  // f
  for (int j = ty; j < 32; j += 8) {
    int y = blockIdx.y * 32 + j;  // d
    tile[j][lx] = in[(size_t)y * NF + x];
  }
  __syncthreads();
  int xo = blockIdx.y * 32 + lx;  // d
  for (int j = ty; j < 32; j += 8) {
    int yo = blockIdx.x * 32 + j;  // f
    out[(size_t)yo * ND + xo] = f2bf(tile[lx][j]);
  }
}

// ---------------------------------------------------------------------------
// bf16 MFMA GEMM v5: round-8 structure + atomic-FREE fused candidate append.
// Per 16-lane row-group: prefix-sum slots, assemble 8-slot segment in LDS,
// two coalesced 16B nt stores -> glist[row][tcol*8..+8). Sentinel 0xFFFFFFFF
// in slot 0 marks segment overflow (>8 candidates, ~never).
__global__ __launch_bounds__(256) void enc_gemm_bf16(
    const unsigned short* __restrict__ Xb, const unsigned short* __restrict__ Wb,
    const float* __restrict__ beta, unsigned short* __restrict__ acts,
    unsigned short* __restrict__ tmax, unsigned* __restrict__ glist) {
  __shared__ __align__(1024) unsigned short SL[2][128 * 64];
  __shared__ unsigned segbuf[4][32];  // per wave: 4 row-segments x 8 u32
  unsigned short* As = SL[0];
  unsigned short* Bs = SL[1];
  const int tid = threadIdx.x;
  const int wave = tid >> 6, lane = tid & 63;
  const int wm = wave >> 1, wn = wave & 1;

  const int orig = blockIdx.y * gridDim.x + blockIdx.x;  // 0..8191
  const int xcd = orig & 7;
  const int local = orig >> 3;          // 0..1023
  const int tcol = local >> 4;          // 0..63
  const int trow = (xcd << 4) + (local & 15);
  const int brow = trow << 7;
  const int bcol = tcol << 7;

  f32x4 acc[4][4] = {};

  const int srow = tid >> 3;                                   // 0..31
  const int scol = (((tid & 7) ^ ((tid >> 3) & 7)) << 3);      // pre-swizzled source chunk
  const unsigned short* gA = Xb + (size_t)(brow + srow) * ND + scol;
  const unsigned short* gB = Wb + (size_t)(bcol + srow) * ND + scol;

  for (int kt = 0; kt < ND; kt += 64) {
#pragma unroll
    for (int i = 0; i < 4; ++i) {
      __builtin_amdgcn_global_load_lds(
          (const __attribute__((address_space(1))) void*)(gA + (size_t)(i * 32) * ND + kt),
          (__attribute__((address_space(3))) void*)(As + (i * 32 + wave * 8) * 64), 16, 0, 0);
      __builtin_amdgcn_global_load_lds(
          (const __attribute__((address_space(1))) void*)(gB + (size_t)(i * 32) * ND + kt),
          (__attribute__((address_space(3))) void*)(Bs + (i * 32 + wave * 8) * 64), 16, 0, 0);
    }
    __syncthreads();
#pragma unroll
    for (int kk = 0; kk < 64; kk += 32) {
      const int chunk = (kk + ((lane >> 4) << 3)) >> 3;  // 0..7 (16B units)
      const int rA = (wm << 6) + (lane & 15);
      const int rB = (wn << 6) + (lane & 15);
      const int sw = chunk ^ (lane & 7);  // row&7 == lane&7 for all frag rows
      bf16x8 a[4], bvv[4];
#pragma unroll
      for (int m = 0; m < 4; ++m)
        a[m] = *(const bf16x8*)&As[(rA + (m << 4)) * 64 + (sw << 3)];
#pragma unroll
      for (int n = 0; n < 4; ++n)
        bvv[n] = *(const bf16x8*)&Bs[(rB + (n << 4)) * 64 + (sw << 3)];
#pragma unroll
      for (int m = 0; m < 4; ++m)
#pragma unroll
        for (int n = 0; n < 4; ++n)
          acc[m][n] = __builtin_amdgcn_mfma_f32_16x16x32_bf16(a[m], bvv[n], acc[m][n], 0, 0, 0);
    }
    __syncthreads();
  }

  // ---- epilogue: acc -> LDS (swizzled 16B slots)
  unsigned short* S = (unsigned short*)SL;  // 128 x 128 shorts (32 KB)
#pragma unroll
  for (int n = 0; n < 4; ++n) {
    float bet = beta[bcol + (wn << 6) + (n << 4) + (lane & 15)];
#pragma unroll
    for (int m = 0; m < 4; ++m) {
#pragma unroll
      for (int r = 0; r < 4; ++r) {
        int row_l = (wm << 6) + (m << 4) + ((lane >> 4) << 2) + r;
        int col_l = (wn << 6) + (n << 4) + (lane & 15);
        float v = fmaxf(acc[m][n][r] + bet, 0.f);
        int slot = (col_l >> 3) ^ (row_l & 7);  // XOR affects low 3 bits only
        S[row_l * 128 + (slot << 3) + (col_l & 7)] = f2bf(v);
      }
    }
  }
  __syncthreads();
  // readback: 8 iters x (16 rows x 16 slots); acts stores + tmax + candidates
#pragma unroll
  for (int i = 0; i < 8; ++i) {
    int row_l = (tid >> 4) + (i << 4);
    int slot = tid & 15;
    u32x4 d = *(const u32x4*)&S[row_l * 128 + (slot << 3)];
    unsigned mx = 0;
#pragma unroll
    for (int q = 0; q < 4; ++q) {
      unsigned lo = d[q] & 0xFFFFu, hi = d[q] >> 16;
      if (lo > mx) mx = lo;
      if (hi > mx) mx = hi;
    }
#pragma unroll
    for (int off = 1; off < 16; off <<= 1) {
      unsigned o = __shfl_xor(mx, off);
      if (o > mx) mx = o;
    }
    int chunk = slot ^ (row_l & 7);  // logical 16B chunk this lane holds
    __builtin_nontemporal_store(
        d, (u32x4*)&acts[(size_t)(brow + row_l) * NF + bcol + (chunk << 3)]);
    if (slot == 0) tmax[(size_t)(brow + row_l) * 64 + tcol] = (unsigned short)mx;

    // -- candidate append (atomic-free)
    int cnt = 0;
#pragma unroll
    for (int q = 0; q < 4; ++q) {
      cnt += ((d[q] & 0xFFFFu) >= THETA0_BITS);
      cnt += ((d[q] >> 16) >= THETA0_BITS);
    }
    int pre = cnt;
#pragma unroll
    for (int off = 1; off < 16; off <<= 1) {
      int v = __shfl_up(pre, off);
      if ((lane & 15) >= off) pre += v;
    }
    int base = pre - cnt;
    int total = __shfl(pre, (lane & 48) + 15);
    unsigned* seg = &segbuf[wave][((lane >> 4) & 3) << 3];
    if ((lane & 15) < 8) seg[lane & 7] = 0u;
    if (total <= 8) {
      int w = base;
#pragma unroll
      for (int q = 0; q < 4; ++q) {
#pragma unroll
        for (int h = 0; h < 2; ++h) {
          unsigned u = h ? (d[q] >> 16) : (d[q] & 0xFFFFu);
          if (u >= THETA0_BITS) {
            seg[w] = (u << 16) | (unsigned)(bcol + (chunk << 3) + q * 2 + h);
            ++w;
          }
        }
      }
    } else if ((lane & 15) == 0) {
      seg[0] = 0xFFFFFFFFu;  // overflow sentinel -> row falls back in ksel
    }
    if ((lane & 7) == 0) {
      int sub = (lane >> 3) & 1;
      u32x4 sv = *(const u32x4*)&seg[sub << 2];
      __builtin_nontemporal_store(
          sv, (u32x4*)&glist[(size_t)(brow + row_l) * CMAX + (tcol << 3) + (sub << 2)]);
    }
  }
}

// ---------------------------------------------------------------------------
// ksel v5: wave-per-row. Fast path: GEMM-built segmented list (2 KB/row; no
// acts read). Validity: no sentinel, n>=k (=> tau_list == true bf16 tau),
// tau >= THETA0+MARG (=> ambiguous band fully inside list). Any wave invalid
// -> whole block runs the round-8 streaming path on acts/tmax.
__global__ __launch_bounds__(256, 6) void ksel_k(
    const unsigned short* __restrict__ acts, const unsigned short* __restrict__ tmax,
    const unsigned* __restrict__ glist,
    const float* __restrict__ x, const float* __restrict__ W_enc,
    const float* __restrict__ beta, const unsigned short* __restrict__ WdecBf,
    const float* __restrict__ dec_bias, const int* __restrict__ kptr,
    float* __restrict__ out_rec, float* __restrict__ g_vals, int* __restrict__ g_idxs) {
  const int tid = threadIdx.x, wave = tid >> 6, lane = tid & 63;
  const int b = blockIdx.x * 4 + wave;
  int k = *kptr; k = k < 1 ? 1 : (k > 64 ? 64 : k);
  const unsigned kk = (unsigned)k;

  __shared__ int stile_s[4][64];
  __shared__ unsigned clist_s[4][CMAX];
  __shared__ unsigned long long aval_s[4][AMAX];
  __shared__ float selv_s[4][64];
  __shared__ int seli_s[4][64];
  __shared__ int ctrC_s[4], ctrW_s[4], ctrA_s[4];
  __shared__ int blkFb;

  int* stile = stile_s[wave];
  unsigned* clist = clist_s[wave];
  unsigned long long* aval = aval_s[wave];
  float* selv = selv_s[wave];
  int* seli = seli_s[wave];

  if (tid == 0) blkFb = 0;
  if (lane == 0) { ctrC_s[wave] = 0; ctrW_s[wave] = 0; ctrA_s[wave] = 0; }

  // ---- fast path: load + compact the segmented list
  bool bad = false;
  {
    const u32x4* seg4 = (const u32x4*)(glist + (size_t)b * CMAX);
#pragma unroll
    for (int ii = 0; ii < 2; ++ii) {
      u32x4 e4 = __builtin_nontemporal_load(&seg4[lane + (ii << 6)]);
#pragma unroll
      for (int q = 0; q < 4; ++q) {
        unsigned e = e4[q];
        if (e) {
          if ((e & 0xFFFFu) >= (unsigned)NF) bad = true;  // sentinel/garbage
          else {
            int p = atomicAdd(&ctrC_s[wave], 1);
            if (p < CMAX) clist[p] = e;
          }
        }
      }
    }
  }
  bad = (__ballot(bad) != 0ull);
  int n = ctrC_s[wave]; if (n > CMAX) n = CMAX;

  // tau via 15-probe bitwise binary search over the list
  unsigned ks[8];
#pragma unroll
  for (int ii = 0; ii < 8; ++ii) {
    int j = lane + (ii << 6);
    ks[ii] = (j < n) ? (clist[j] >> 16) : 0u;
  }
  unsigned T = 0;
  for (int bit = 14; bit >= 0; --bit) {
    unsigned probe = T | (1u << bit);
    int c = 0;
#pragma unroll
    for (int ii = 0; ii < 8; ++ii) c += (ks[ii] >= probe);
#pragma unroll
    for (int off = 32; off; off >>= 1) c += __shfl_xor(c, off);
    if (c >= (int)kk) T = probe;
  }
  float tauf = bfbits2f(T);

  bool valid = !bad && (n >= k) && (tauf >= THETA0 + MARG);
  if (lane == 0 && !valid) atomicOr(&blkFb, 1);
  __syncthreads();

  if (blkFb) {
    // ---- fallback: round-8 streaming path (block-uniform)
    unsigned tm = tmax[(size_t)b * 64 + lane];
    unsigned T2 = 0;
    for (int bit = 14; bit >= 0; --bit) {
      unsigned probe = T2 | (1u << bit);
      int c = __popcll(__ballot(tm >= probe));
      if (c >= k) T2 = probe;
    }
    const float Lf = bfbits2f(T2) - MARG;
    if (lane == 0) ctrC_s[wave] = 0;
    {
      bool sel = bfbits2f(tm) >= Lf;
      unsigned long long mask = __ballot(sel);
      int pos = __popcll(mask & ((1ull << lane) - 1ull));
      if (sel) stile[pos] = lane;
    }
    __syncthreads();
    const int nsel = __popcll(__ballot(bfbits2f(tm) >= Lf));
    const u32x4* row16 = (const u32x4*)(acts + (size_t)b * NF);
    for (int t = 0; t < nsel; t += 4) {
      int tt = t + (lane >> 4);
      if (tt < nsel) {
        int tile = stile[tt];
        u32x4 v = __builtin_nontemporal_load(&row16[tile * 16 + (lane & 15)]);
        int base = tile * 128 + (lane & 15) * 8;
#pragma unroll
        for (int q = 0; q < 4; ++q) {
#pragma unroll
          for (int h = 0; h < 2; ++h) {
            unsigned u = h ? (v[q] >> 16) : (v[q] & 0xFFFFu);
            if (bfbits2f(u) >= Lf) {
              int p = atomicAdd(&ctrC_s[wave], 1);
              if (p < CMAX) clist[p] = (u << 16) | (unsigned)(base + q * 2 + h);
            }
          }
        }
      }
    }
    __syncthreads();
    n = ctrC_s[wave]; if (n > CMAX) n = CMAX;
#pragma unroll
    for (int ii = 0; ii < 8; ++ii) {
      int j = lane + (ii << 6);
      ks[ii] = (j < n) ? (clist[j] >> 16) : 0u;
    }
    T = 0;
    for (int bit = 14; bit >= 0; --bit) {
      unsigned probe = T | (1u << bit);
      int c = 0;
#pragma unroll
      for (int ii = 0; ii < 8; ++ii) c += (ks[ii] >= probe);
#pragma unroll
      for (int off = 32; off; off >>= 1) c += __shfl_xor(c, off);
      if (c >= (int)kk) T = probe;
    }
    tauf = bfbits2f(T);
  }

  const float thrW = tauf + MARG;
  const float thrA = tauf - MARG;

  // ---- classify: winners (bf16 value final) / ambiguous band
  for (int j = lane; j < n; j += 64) {
    unsigned e = clist[j];
    float v = bfbits2f(e >> 16);
    int idx = (int)(e & 0xFFFFu);
    if (v > thrW) {
      int p = atomicAdd(&ctrW_s[wave], 1);
      if (p < 63) { selv[p] = v; seli[p] = idx; }  // count(v > tau) <= k-1
    } else if (v >= thrA) {
      int p = atomicAdd(&ctrA_s[wave], 1);
      if (p < AMAX) aval[p] = (unsigned long long)(unsigned)idx;
    }
  }
  __syncthreads();
  int c = ctrW_s[wave]; if (c > 63) c = 63; if (c > k - 1) c = k - 1;
  int na = ctrA_s[wave]; if (na > AMAX) na = AMAX;

  // ---- exact fp32 dots for ambiguous (2-wide)
  float xr[12];
#pragma unroll
  for (int cc = 0; cc < 12; ++cc)
    xr[cc] = __builtin_nontemporal_load(&x[(size_t)b * ND + lane + 64 * cc]);
  for (int j = 0; j < na; j += 2) {
    int f0 = (int)(unsigned)aval[j];
    int f1 = (j + 1 < na) ? (int)(unsigned)aval[j + 1] : f0;
    const float* w0 = W_enc + (size_t)f0 * ND;
    const float* w1 = W_enc + (size_t)f1 * ND;
    float s0 = 0.f, s1 = 0.f;
#pragma unroll
    for (int cc = 0; cc < 12; ++cc) {
      s0 = fmaf(xr[cc], w0[lane + 64 * cc], s0);
      s1 = fmaf(xr[cc], w1[lane + 64 * cc], s1);
    }
#pragma unroll
    for (int off = 32; off; off >>= 1) {
      s0 += __shfl_xor(s0, off);
      s1 += __shfl_xor(s1, off);
    }
    if (lane == 0) {
      float v0 = fmaxf(s0 + beta[f0], 0.f);
      aval[j] = (((unsigned long long)__float_as_uint(v0)) << 13) | (unsigned)(8191 - f0);
      if (j + 1 < na) {
        float v1 = fmaxf(s1 + beta[f1], 0.f);
        aval[j + 1] = (((unsigned long long)__float_as_uint(v1)) << 13) | (unsigned)(8191 - f1);
      }
    }
  }
  __syncthreads();

  // ---- select top (k-c) ambiguous by (exact val desc, idx asc)
  {
    unsigned long long p0 = (lane < na) ? aval[lane] : 0ull;
    unsigned long long p1 = (lane + 64 < na) ? aval[lane + 64] : 0ull;
    int rounds = k - c; if (rounds < 0) rounds = 0;
    for (int r = 0; r < rounds; ++r) {
      unsigned long long m = p0 > p1 ? p0 : p1;
#pragma unroll
      for (int off = 32; off; off >>= 1) {
        unsigned long long o = __shfl_xor(m, off);
        if (o > m) m = o;
      }
      if (lane == 0) {
        if (m) { selv[c + r] = __uint_as_float((unsigned)(m >> 13)); seli[c + r] = 8191 - (int)(m & 0x1FFFull); }
        else   { selv[c + r] = 0.f; seli[c + r] = 0; }
      }
      if (p0 == m) p0 = 0;
      if (p1 == m) p1 = 0;
    }
  }
  __syncthreads();

  if (lane < k) {
    g_vals[(size_t)b * 64 + lane] = selv[lane];
    g_idxs[(size_t)b * 64 + lane] = seli[lane];
  }

  // ---- fused reconstruction (bf16 decoder gathers, cached)
  float acc[12];
#pragma unroll
  for (int cc = 0; cc < 6; ++cc) {
    float2 db = *(const float2*)&dec_bias[cc * 128 + lane * 2];
    acc[2 * cc] = db.x; acc[2 * cc + 1] = db.y;
  }
#define RECON_TERM(r)                                                          \
  {                                                                            \
    int f = seli[r]; float v = selv[r];                                        \
    const unsigned short* wd = WdecBf + (size_t)f * ND;                        \
    _Pragma("unroll")                                                          \
    for (int cc = 0; cc < 6; ++cc) {                                           \
      unsigned pr = *(const unsigned*)&wd[cc * 128 + lane * 2];                \
      acc[2 * cc] = fmaf(v, bfbits2f(pr & 0xFFFFu), acc[2 * cc]);              \
      acc[2 * cc + 1] = fmaf(v, bfbits2f(pr >> 16), acc[2 * cc + 1]);          \
    }                                                                          \
  }
  if (k == 32) {
#pragma unroll
    for (int r = 0; r < 32; ++r) RECON_TERM(r)
  } else {
    for (int r = 0; r < k; ++r) RECON_TERM(r)
  }
#pragma unroll
  for (int cc = 0; cc < 6; ++cc) {
    f32x2 st = {acc[2 * cc], acc[2 * cc + 1]};
    __builtin_nontemporal_store(st, (f32x2*)&out_rec[(size_t)b * ND + cc * 128 + lane * 2]);
  }
}

// ---------------------------------------------------------------------------
__global__ __launch_bounds__(256) void d2_sparse_k(
    const float* __restrict__ g_vals, const int* __restrict__ g_idxs,
    const int* __restrict__ kptr, float* __restrict__ out_sc) {
  const int b = blockIdx.x, tid = threadIdx.x;
  int k = *kptr; k = k < 1 ? 1 : (k > 64 ? 64 : k);
  __shared__ float row[NF];
  __shared__ float sv[64];
  __shared__ int si[64];
  if (tid < k) { sv[tid] = g_vals[(size_t)b * 64 + tid]; si[tid] = g_idxs[(size_t)b * 64 + tid]; }
  float4* r4 = (float4*)row;
#pragma unroll
  for (int i = 0; i < 8; ++i) r4[tid + 256 * i] = make_float4(0.f, 0.f, 0.f, 0.f);
  __syncthreads();
  if (tid < k) row[si[tid]] = sv[tid];
  __syncthreads();
  f32x4* o4 = (f32x4*)(out_sc + (size_t)b * NF);
  const f32x4* r4v = (const f32x4*)row;
#pragma unroll
  for (int i = 0; i < 8; ++i)
    __builtin_nontemporal_store(r4v[tid + 256 * i], &o4[tid + 256 * i]);
}

// ---------------------------------------------------------------------------
extern "C" void kernel_launch(void* const* d_in, const int* in_sizes, int n_in,
                              void* d_out, int out_size, void* d_ws, size_t ws_size,
                              hipStream_t stream) {
  const float* x        = (const float*)d_in[0];
  const float* W_enc    = (const float*)d_in[1];
  const float* b_enc    = (const float*)d_in[2];
  const float* W_dec    = (const float*)d_in[3];
  const float* dec_bias = (const float*)d_in[4];
  const int*   kptr     = (const int*)d_in[5];

  float* out_rec = (float*)d_out;
  float* out_sc  = (float*)d_out + (size_t)NB * ND;

  // scratch carved from the sparse-code output region (rewritten by d2 last)
  char* scb = (char*)out_sc;
  unsigned short* acts  = (unsigned short*)scb;                // 256 MB
  unsigned short* Xbf   = (unsigned short*)(scb + 268435456);  // 24 MB
  unsigned short* Wbf   = (unsigned short*)(scb + 293601280);  // 12 MB
  unsigned*       glist = (unsigned*)(scb + 306184192);        // 32 MB (16384*512*4)

  char* ws = (char*)d_ws;
  unsigned short* WdecBf = (unsigned short*)ws;        // 12,582,912 B
  float* beta   = (float*)(ws + 12582912);             //     32,768 B
  float* g_vals = (float*)(ws + 12615680);             //  4,194,304 B
  int*   g_idxs = (int*)(ws + 16809984);               //  4,194,304 B
  unsigned short* tmax = (unsigned short*)(ws + 21004288); // 2,097,152 B

  cvt_bf16_k<<<(NB * ND) / 2048, 256, 0, stream>>>(x, Xbf);
  cvt_bf16_k<<<(NF * ND) / 2048, 256, 0, stream>>>(W_enc, Wbf);
  beta_k<<<NF / 4, 256, 0, stream>>>(W_enc, b_enc, dec_bias, beta);
  transpose_bf_k<<<dim3(NF / 32, ND / 32), 256, 0, stream>>>(W_dec, WdecBf);
  enc_gemm_bf16<<<dim3(NF / 128, NB / 128), 256, 0, stream>>>(Xbf, Wbf, beta, acts,
                                                              tmax, glist);
  ksel_k<<<NB / 4, 256, 0, stream>>>(acts, tmax, glist, x, W_enc, beta, WdecBf,
                                     dec_bias, kptr, out_rec, g_vals, g_idxs);
  d2_sparse_k<<<NB, 256, 0, stream>>>(g_vals, g_idxs, kptr, out_sc);
}

// Round 11
// 656.349 us; speedup vs baseline: 1.4334x; 1.0310x over previous
//
#include <hip/hip_runtime.h>

#define NB 16384
#define ND 768
#define NF 8192
#define CMAX 512        // ksel compact list cap per row
#define SEGW 16         // glist slots per (row,tile) segment
#define GSEG 1024       // glist u32 per row (64 tiles x 16 slots)
#define AMAX 128        // ambiguous cap per row (expect ~13)
#define MARG 0.07f      // classification margin (>= 2x bf16-GEMM act error bound)
#define THETA0 2.0f     // GEMM-side candidate threshold (bf16-exact)
#define THETA0_BITS 0x4000u

typedef __attribute__((ext_vector_type(8))) short bf16x8;
typedef __attribute__((ext_vector_type(4))) float f32x4;
typedef __attribute__((ext_vector_type(4))) unsigned int u32x4;
typedef __attribute__((ext_vector_type(2))) float f32x2;

__device__ inline unsigned short f2bf(float f) {
  unsigned u = __float_as_uint(f);
  unsigned r = (u + 0x7FFFu + ((u >> 16) & 1u)) >> 16;
  return (unsigned short)r;
}
__device__ inline float bfbits2f(unsigned u16) { return __uint_as_float(u16 << 16); }

// ---------------------------------------------------------------------------
__global__ __launch_bounds__(256) void cvt_bf16_k(const float* __restrict__ in,
                                                  unsigned short* __restrict__ out) {
  size_t t = (size_t)blockIdx.x * 256 + threadIdx.x;
  const float4* i4 = (const float4*)in;
  float4 a = i4[t * 2], b = i4[t * 2 + 1];
  ushort4 lo = make_ushort4(f2bf(a.x), f2bf(a.y), f2bf(a.z), f2bf(a.w));
  ushort4 hi = make_ushort4(f2bf(b.x), f2bf(b.y), f2bf(b.z), f2bf(b.w));
  ((ushort4*)out)[t * 2] = lo;
  ((ushort4*)out)[t * 2 + 1] = hi;
}

// ---------------------------------------------------------------------------
__global__ __launch_bounds__(256) void beta_k(const float* __restrict__ W_enc,
                                              const float* __restrict__ b_enc,
                                              const float* __restrict__ dec_bias,
                                              float* __restrict__ beta) {
  int f = blockIdx.x * 4 + (threadIdx.x >> 6);
  int lane = threadIdx.x & 63;
  const float* wr = W_enc + (size_t)f * ND;
  float s = 0.f;
  for (int d = lane; d < ND; d += 64) s += dec_bias[d] * wr[d];
  for (int off = 32; off; off >>= 1) s += __shfl_down(s, off);
  if (lane == 0) beta[f] = b_enc[f] - s;
}

// ---------------------------------------------------------------------------
__global__ __launch_bounds__(256) void transpose_bf_k(const float* __restrict__ in,
                                                      unsigned short* __restrict__ out) {
  __shared__ float tile[32][33];
  int lx = threadIdx.x & 31;
  int ty = threadIdx.x >> 5;
  int x = blockIdx.x * 32 + lx;  // f
  for (int j = ty; j < 32; j += 8) {
    int y = blockIdx.y * 32 + j;  // d
    tile[j][lx] = in[(size_t)y * NF + x];
  }
  __syncthreads();
  int xo = blockIdx.y * 32 + lx;  // d
  for (int j = ty; j < 32; j += 8) {
    int yo = blockIdx.x * 32 + j;  // f
    out[(size_t)yo * ND + xo] = f2bf(tile[lx][j]);
  }
}

// ---------------------------------------------------------------------------
// bf16 MFMA GEMM v6: round-8 structure + cheap fused candidate append.
// Per readback iteration, each row's 16 lanes are one wave -> per-wave LDS
// segment buffer (16 slots/row), LDS-atomic append (rare), sentinel on
// overflow (P ~ 3e-9), coalesced 64B flush to glist[row][tcol*16..+16).
__global__ __launch_bounds__(256) void enc_gemm_bf16(
    const unsigned short* __restrict__ Xb, const unsigned short* __restrict__ Wb,
    const float* __restrict__ beta, unsigned short* __restrict__ acts,
    unsigned short* __restrict__ tmax, unsigned* __restrict__ glist) {
  __shared__ __align__(1024) unsigned short SL[2][128 * 64];
  __shared__ unsigned wseg[4][4][SEGW];  // [wave][row-in-wave][slot]
  __shared__ unsigned wcnt[4][4];
  unsigned short* As = SL[0];
  unsigned short* Bs = SL[1];
  const int tid = threadIdx.x;
  const int wave = tid >> 6, lane = tid & 63;
  const int wm = wave >> 1, wn = wave & 1;

  const int orig = blockIdx.y * gridDim.x + blockIdx.x;  // 0..8191
  const int xcd = orig & 7;
  const int local = orig >> 3;          // 0..1023
  const int tcol = local >> 4;          // 0..63
  const int trow = (xcd << 4) + (local & 15);
  const int brow = trow << 7;
  const int bcol = tcol << 7;

  f32x4 acc[4][4] = {};

  const int srow = tid >> 3;                                   // 0..31
  const int scol = (((tid & 7) ^ ((tid >> 3) & 7)) << 3);      // pre-swizzled source chunk
  const unsigned short* gA = Xb + (size_t)(brow + srow) * ND + scol;
  const unsigned short* gB = Wb + (size_t)(bcol + srow) * ND + scol;

  for (int kt = 0; kt < ND; kt += 64) {
#pragma unroll
    for (int i = 0; i < 4; ++i) {
      __builtin_amdgcn_global_load_lds(
          (const __attribute__((address_space(1))) void*)(gA + (size_t)(i * 32) * ND + kt),
          (__attribute__((address_space(3))) void*)(As + (i * 32 + wave * 8) * 64), 16, 0, 0);
      __builtin_amdgcn_global_load_lds(
          (const __attribute__((address_space(1))) void*)(gB + (size_t)(i * 32) * ND + kt),
          (__attribute__((address_space(3))) void*)(Bs + (i * 32 + wave * 8) * 64), 16, 0, 0);
    }
    __syncthreads();
#pragma unroll
    for (int kk = 0; kk < 64; kk += 32) {
      const int chunk = (kk + ((lane >> 4) << 3)) >> 3;  // 0..7 (16B units)
      const int rA = (wm << 6) + (lane & 15);
      const int rB = (wn << 6) + (lane & 15);
      const int sw = chunk ^ (lane & 7);  // row&7 == lane&7 for all frag rows
      bf16x8 a[4], bvv[4];
#pragma unroll
      for (int m = 0; m < 4; ++m)
        a[m] = *(const bf16x8*)&As[(rA + (m << 4)) * 64 + (sw << 3)];
#pragma unroll
      for (int n = 0; n < 4; ++n)
        bvv[n] = *(const bf16x8*)&Bs[(rB + (n << 4)) * 64 + (sw << 3)];
#pragma unroll
      for (int m = 0; m < 4; ++m)
#pragma unroll
        for (int n = 0; n < 4; ++n)
          acc[m][n] = __builtin_amdgcn_mfma_f32_16x16x32_bf16(a[m], bvv[n], acc[m][n], 0, 0, 0);
    }
    __syncthreads();
  }

  // ---- epilogue: acc -> LDS (swizzled 16B slots)
  unsigned short* S = (unsigned short*)SL;  // 128 x 128 shorts (32 KB)
#pragma unroll
  for (int n = 0; n < 4; ++n) {
    float bet = beta[bcol + (wn << 6) + (n << 4) + (lane & 15)];
#pragma unroll
    for (int m = 0; m < 4; ++m) {
#pragma unroll
      for (int r = 0; r < 4; ++r) {
        int row_l = (wm << 6) + (m << 4) + ((lane >> 4) << 2) + r;
        int col_l = (wn << 6) + (n << 4) + (lane & 15);
        float v = fmaxf(acc[m][n][r] + bet, 0.f);
        int slot = (col_l >> 3) ^ (row_l & 7);  // XOR affects low 3 bits only
        S[row_l * 128 + (slot << 3) + (col_l & 7)] = f2bf(v);
      }
    }
  }
  __syncthreads();
  // readback: 8 iters x (16 rows x 16 slots); acts + tmax + candidate segments
  const int lr = lane >> 4;    // row-in-wave 0..3
  const int ls = lane & 15;    // slot-in-row 0..15
#pragma unroll
  for (int i = 0; i < 8; ++i) {
    int row_l = (tid >> 4) + (i << 4);
    // zero my segment slot + counter (wave-synchronous, no barrier needed)
    wseg[wave][lr][ls] = 0u;
    if (ls == 0) wcnt[wave][lr] = 0u;

    u32x4 d = *(const u32x4*)&S[row_l * 128 + (ls << 3)];
    unsigned mx = 0;
#pragma unroll
    for (int q = 0; q < 4; ++q) {
      unsigned lo = d[q] & 0xFFFFu, hi = d[q] >> 16;
      if (lo > mx) mx = lo;
      if (hi > mx) mx = hi;
    }
#pragma unroll
    for (int off = 1; off < 16; off <<= 1) {
      unsigned o = __shfl_xor(mx, off);
      if (o > mx) mx = o;
    }
    int chunk = ls ^ (row_l & 7);  // logical 16B chunk this lane holds
    __builtin_nontemporal_store(
        d, (u32x4*)&acts[(size_t)(brow + row_l) * NF + bcol + (chunk << 3)]);
    if (ls == 0) tmax[(size_t)(brow + row_l) * 64 + tcol] = (unsigned short)mx;

    // candidate append (LDS atomic; E[candidates/lane] ~ 0.18)
#pragma unroll
    for (int q = 0; q < 4; ++q) {
#pragma unroll
      for (int h = 0; h < 2; ++h) {
        unsigned u = h ? (d[q] >> 16) : (d[q] & 0xFFFFu);
        if (u >= THETA0_BITS) {
          unsigned p = atomicAdd(&wcnt[wave][lr], 1u);
          if (p < SEGW)
            wseg[wave][lr][p] = (u << 16) | (unsigned)(bcol + (chunk << 3) + q * 2 + h);
        }
      }
    }
    if (ls == 0 && wcnt[wave][lr] > SEGW) wseg[wave][lr][0] = 0xFFFFFFFFu;  // sentinel
    // flush: 16 lanes x u32 = 64B full line per row
    unsigned sv = wseg[wave][lr][ls];
    __builtin_nontemporal_store(
        sv, &glist[(size_t)(brow + row_l) * GSEG + (tcol << 4) + ls]);
  }
}

// ---------------------------------------------------------------------------
// ksel v6: wave-per-row. Fast path: GEMM-built segmented list (4 KB/row; no
// acts read). Validity: no sentinel/garbage, n>=k (=> tau_list == true bf16
// tau), tau >= THETA0+MARG (=> ambiguous band fully inside list). Invalid ->
// whole block runs round-8 streaming path on acts/tmax (P ~ 1e-3 per launch).
__global__ __launch_bounds__(256, 6) void ksel_k(
    const unsigned short* __restrict__ acts, const unsigned short* __restrict__ tmax,
    const unsigned* __restrict__ glist,
    const float* __restrict__ x, const float* __restrict__ W_enc,
    const float* __restrict__ beta, const unsigned short* __restrict__ WdecBf,
    const float* __restrict__ dec_bias, const int* __restrict__ kptr,
    float* __restrict__ out_rec, float* __restrict__ g_vals, int* __restrict__ g_idxs) {
  const int tid = threadIdx.x, wave = tid >> 6, lane = tid & 63;
  const int b = blockIdx.x * 4 + wave;
  int k = *kptr; k = k < 1 ? 1 : (k > 64 ? 64 : k);
  const unsigned kk = (unsigned)k;

  __shared__ int stile_s[4][64];
  __shared__ unsigned clist_s[4][CMAX];
  __shared__ unsigned long long aval_s[4][AMAX];
  __shared__ float selv_s[4][64];
  __shared__ int seli_s[4][64];
  __shared__ int ctrC_s[4], ctrW_s[4], ctrA_s[4];
  __shared__ int blkFb;

  int* stile = stile_s[wave];
  unsigned* clist = clist_s[wave];
  unsigned long long* aval = aval_s[wave];
  float* selv = selv_s[wave];
  int* seli = seli_s[wave];

  if (tid == 0) blkFb = 0;
  if (lane == 0) { ctrC_s[wave] = 0; ctrW_s[wave] = 0; ctrA_s[wave] = 0; }

  // ---- fast path: load + compact the segmented list (4 KB/row)
  bool bad = false;
  {
    const u32x4* seg4 = (const u32x4*)(glist + (size_t)b * GSEG);
#pragma unroll
    for (int ii = 0; ii < 4; ++ii) {
      u32x4 e4 = __builtin_nontemporal_load(&seg4[lane + (ii << 6)]);
#pragma unroll
      for (int q = 0; q < 4; ++q) {
        unsigned e = e4[q];
        if (e) {
          if ((e & 0xFFFFu) >= (unsigned)NF) bad = true;  // sentinel/garbage
          else {
            int p = atomicAdd(&ctrC_s[wave], 1);
            if (p < CMAX) clist[p] = e;
          }
        }
      }
    }
  }
  bad = (__ballot(bad) != 0ull);
  int n = ctrC_s[wave]; if (n > CMAX) n = CMAX;

  // tau via 15-probe bitwise binary search over the list
  unsigned ks[8];
#pragma unroll
  for (int ii = 0; ii < 8; ++ii) {
    int j = lane + (ii << 6);
    ks[ii] = (j < n) ? (clist[j] >> 16) : 0u;
  }
  unsigned T = 0;
  for (int bit = 14; bit >= 0; --bit) {
    unsigned probe = T | (1u << bit);
    int c = 0;
#pragma unroll
    for (int ii = 0; ii < 8; ++ii) c += (ks[ii] >= probe);
#pragma unroll
    for (int off = 32; off; off >>= 1) c += __shfl_xor(c, off);
    if (c >= (int)kk) T = probe;
  }
  float tauf = bfbits2f(T);

  bool valid = !bad && (n >= k) && (tauf >= THETA0 + MARG);
  if (lane == 0 && !valid) atomicOr(&blkFb, 1);
  __syncthreads();

  if (blkFb) {
    // ---- fallback: round-8 streaming path (block-uniform)
    unsigned tm = tmax[(size_t)b * 64 + lane];
    unsigned T2 = 0;
    for (int bit = 14; bit >= 0; --bit) {
      unsigned probe = T2 | (1u << bit);
      int c = __popcll(__ballot(tm >= probe));
      if (c >= k) T2 = probe;
    }
    const float Lf = bfbits2f(T2) - MARG;
    if (lane == 0) ctrC_s[wave] = 0;
    {
      bool sel = bfbits2f(tm) >= Lf;
      unsigned long long mask = __ballot(sel);
      int pos = __popcll(mask & ((1ull << lane) - 1ull));
      if (sel) stile[pos] = lane;
    }
    __syncthreads();
    const int nsel = __popcll(__ballot(bfbits2f(tm) >= Lf));
    const u32x4* row16 = (const u32x4*)(acts + (size_t)b * NF);
    for (int t = 0; t < nsel; t += 4) {
      int tt = t + (lane >> 4);
      if (tt < nsel) {
        int tile = stile[tt];
        u32x4 v = __builtin_nontemporal_load(&row16[tile * 16 + (lane & 15)]);
        int base = tile * 128 + (lane & 15) * 8;
#pragma unroll
        for (int q = 0; q < 4; ++q) {
#pragma unroll
          for (int h = 0; h < 2; ++h) {
            unsigned u = h ? (v[q] >> 16) : (v[q] & 0xFFFFu);
            if (bfbits2f(u) >= Lf) {
              int p = atomicAdd(&ctrC_s[wave], 1);
              if (p < CMAX) clist[p] = (u << 16) | (unsigned)(base + q * 2 + h);
            }
          }
        }
      }
    }
    __syncthreads();
    n = ctrC_s[wave]; if (n > CMAX) n = CMAX;
#pragma unroll
    for (int ii = 0; ii < 8; ++ii) {
      int j = lane + (ii << 6);
      ks[ii] = (j < n) ? (clist[j] >> 16) : 0u;
    }
    T = 0;
    for (int bit = 14; bit >= 0; --bit) {
      unsigned probe = T | (1u << bit);
      int c = 0;
#pragma unroll
      for (int ii = 0; ii < 8; ++ii) c += (ks[ii] >= probe);
#pragma unroll
      for (int off = 32; off; off >>= 1) c += __shfl_xor(c, off);
      if (c >= (int)kk) T = probe;
    }
    tauf = bfbits2f(T);
  }

  const float thrW = tauf + MARG;
  const float thrA = tauf - MARG;

  // ---- classify: winners (bf16 value final) / ambiguous band
  for (int j = lane; j < n; j += 64) {
    unsigned e = clist[j];
    float v = bfbits2f(e >> 16);
    int idx = (int)(e & 0xFFFFu);
    if (v > thrW) {
      int p = atomicAdd(&ctrW_s[wave], 1);
      if (p < 63) { selv[p] = v; seli[p] = idx; }  // count(v > tau) <= k-1
    } else if (v >= thrA) {
      int p = atomicAdd(&ctrA_s[wave], 1);
      if (p < AMAX) aval[p] = (unsigned long long)(unsigned)idx;
    }
  }
  __syncthreads();
  int c = ctrW_s[wave]; if (c > 63) c = 63; if (c > k - 1) c = k - 1;
  int na = ctrA_s[wave]; if (na > AMAX) na = AMAX;

  // ---- exact fp32 dots for ambiguous (2-wide)
  float xr[12];
#pragma unroll
  for (int cc = 0; cc < 12; ++cc)
    xr[cc] = __builtin_nontemporal_load(&x[(size_t)b * ND + lane + 64 * cc]);
  for (int j = 0; j < na; j += 2) {
    int f0 = (int)(unsigned)aval[j];
    int f1 = (j + 1 < na) ? (int)(unsigned)aval[j + 1] : f0;
    const float* w0 = W_enc + (size_t)f0 * ND;
    const float* w1 = W_enc + (size_t)f1 * ND;
    float s0 = 0.f, s1 = 0.f;
#pragma unroll
    for (int cc = 0; cc < 12; ++cc) {
      s0 = fmaf(xr[cc], w0[lane + 64 * cc], s0);
      s1 = fmaf(xr[cc], w1[lane + 64 * cc], s1);
    }
#pragma unroll
    for (int off = 32; off; off >>= 1) {
      s0 += __shfl_xor(s0, off);
      s1 += __shfl_xor(s1, off);
    }
    if (lane == 0) {
      float v0 = fmaxf(s0 + beta[f0], 0.f);
      aval[j] = (((unsigned long long)__float_as_uint(v0)) << 13) | (unsigned)(8191 - f0);
      if (j + 1 < na) {
        float v1 = fmaxf(s1 + beta[f1], 0.f);
        aval[j + 1] = (((unsigned long long)__float_as_uint(v1)) << 13) | (unsigned)(8191 - f1);
      }
    }
  }
  __syncthreads();

  // ---- select top (k-c) ambiguous by (exact val desc, idx asc)
  {
    unsigned long long p0 = (lane < na) ? aval[lane] : 0ull;
    unsigned long long p1 = (lane + 64 < na) ? aval[lane + 64] : 0ull;
    int rounds = k - c; if (rounds < 0) rounds = 0;
    for (int r = 0; r < rounds; ++r) {
      unsigned long long m = p0 > p1 ? p0 : p1;
#pragma unroll
      for (int off = 32; off; off >>= 1) {
        unsigned long long o = __shfl_xor(m, off);
        if (o > m) m = o;
      }
      if (lane == 0) {
        if (m) { selv[c + r] = __uint_as_float((unsigned)(m >> 13)); seli[c + r] = 8191 - (int)(m & 0x1FFFull); }
        else   { selv[c + r] = 0.f; seli[c + r] = 0; }
      }
      if (p0 == m) p0 = 0;
      if (p1 == m) p1 = 0;
    }
  }
  __syncthreads();

  if (lane < k) {
    g_vals[(size_t)b * 64 + lane] = selv[lane];
    g_idxs[(size_t)b * 64 + lane] = seli[lane];
  }

  // ---- fused reconstruction (bf16 decoder gathers, cached)
  float acc[12];
#pragma unroll
  for (int cc = 0; cc < 6; ++cc) {
    float2 db = *(const float2*)&dec_bias[cc * 128 + lane * 2];
    acc[2 * cc] = db.x; acc[2 * cc + 1] = db.y;
  }
#define RECON_TERM(r)                                                          \
  {                                                                            \
    int f = seli[r]; float v = selv[r];                                        \
    const unsigned short* wd = WdecBf + (size_t)f * ND;                        \
    _Pragma("unroll")                                                          \
    for (int cc = 0; cc < 6; ++cc) {                                           \
      unsigned pr = *(const unsigned*)&wd[cc * 128 + lane * 2];                \
      acc[2 * cc] = fmaf(v, bfbits2f(pr & 0xFFFFu), acc[2 * cc]);              \
      acc[2 * cc + 1] = fmaf(v, bfbits2f(pr >> 16), acc[2 * cc + 1]);          \
    }                                                                          \
  }
  if (k == 32) {
#pragma unroll
    for (int r = 0; r < 32; ++r) RECON_TERM(r)
  } else {
    for (int r = 0; r < k; ++r) RECON_TERM(r)
  }
#pragma unroll
  for (int cc = 0; cc < 6; ++cc) {
    f32x2 st = {acc[2 * cc], acc[2 * cc + 1]};
    __builtin_nontemporal_store(st, (f32x2*)&out_rec[(size_t)b * ND + cc * 128 + lane * 2]);
  }
}

// ---------------------------------------------------------------------------
__global__ __launch_bounds__(256) void d2_sparse_k(
    const float* __restrict__ g_vals, const int* __restrict__ g_idxs,
    const int* __restrict__ kptr, float* __restrict__ out_sc) {
  const int b = blockIdx.x, tid = threadIdx.x;
  int k = *kptr; k = k < 1 ? 1 : (k > 64 ? 64 : k);
  __shared__ float row[NF];
  __shared__ float sv[64];
  __shared__ int si[64];
  if (tid < k) { sv[tid] = g_vals[(size_t)b * 64 + tid]; si[tid] = g_idxs[(size_t)b * 64 + tid]; }
  float4* r4 = (float4*)row;
#pragma unroll
  for (int i = 0; i < 8; ++i) r4[tid + 256 * i] = make_float4(0.f, 0.f, 0.f, 0.f);
  __syncthreads();
  if (tid < k) row[si[tid]] = sv[tid];
  __syncthreads();
  f32x4* o4 = (f32x4*)(out_sc + (size_t)b * NF);
  const f32x4* r4v = (const f32x4*)row;
#pragma unroll
  for (int i = 0; i < 8; ++i)
    __builtin_nontemporal_store(r4v[tid + 256 * i], &o4[tid + 256 * i]);
}

// ---------------------------------------------------------------------------
extern "C" void kernel_launch(void* const* d_in, const int* in_sizes, int n_in,
                              void* d_out, int out_size, void* d_ws, size_t ws_size,
                              hipStream_t stream) {
  const float* x        = (const float*)d_in[0];
  const float* W_enc    = (const float*)d_in[1];
  const float* b_enc    = (const float*)d_in[2];
  const float* W_dec    = (const float*)d_in[3];
  const float* dec_bias = (const float*)d_in[4];
  const int*   kptr     = (const int*)d_in[5];

  float* out_rec = (float*)d_out;
  float* out_sc  = (float*)d_out + (size_t)NB * ND;

  // scratch carved from the sparse-code output region (rewritten by d2 last)
  char* scb = (char*)out_sc;
  unsigned short* acts  = (unsigned short*)scb;                // 256 MB
  unsigned short* Xbf   = (unsigned short*)(scb + 268435456);  // 24 MB
  unsigned short* Wbf   = (unsigned short*)(scb + 293601280);  // 12 MB
  unsigned*       glist = (unsigned*)(scb + 306184192);        // 64 MB (16384*1024*4)

  char* ws = (char*)d_ws;
  unsigned short* WdecBf = (unsigned short*)ws;        // 12,582,912 B
  float* beta   = (float*)(ws + 12582912);             //     32,768 B
  float* g_vals = (float*)(ws + 12615680);             //  4,194,304 B
  int*   g_idxs = (int*)(ws + 16809984);               //  4,194,304 B
  unsigned short* tmax = (unsigned short*)(ws + 21004288); // 2,097,152 B

  cvt_bf16_k<<<(NB * ND) / 2048, 256, 0, stream>>>(x, Xbf);
  cvt_bf16_k<<<(NF * ND) / 2048, 256, 0, stream>>>(W_enc, Wbf);
  beta_k<<<NF / 4, 256, 0, stream>>>(W_enc, b_enc, dec_bias, beta);
  transpose_bf_k<<<dim3(NF / 32, ND / 32), 256, 0, stream>>>(W_dec, WdecBf);
  enc_gemm_bf16<<<dim3(NF / 128, NB / 128), 256, 0, stream>>>(Xbf, Wbf, beta, acts,
                                                              tmax, glist);
  ksel_k<<<NB / 4, 256, 0, stream>>>(acts, tmax, glist, x, W_enc, beta, WdecBf,
                                     dec_bias, kptr, out_rec, g_vals, g_idxs);
  d2_sparse_k<<<NB, 256, 0, stream>>>(g_vals, g_idxs, kptr, out_sc);
}

// Round 12
// 646.924 us; speedup vs baseline: 1.4543x; 1.0146x over previous
//
#include <hip/hip_runtime.h>

#define NB 16384
#define ND 768
#define NF 8192
#define CMAX 512        // ksel compact list cap per row
#define SEGW 16         // glist slots per (row,tile) segment
#define GSEG 1024       // glist u32 per row (64 tiles x 16 slots)
#define AMAX 128        // ambiguous cap per row (expect ~13)
#define MARG 0.07f      // classification margin (>= 2x bf16-GEMM act error bound)
#define THETA0 2.0f     // GEMM-side candidate threshold (bf16-exact)
#define THETA0_BITS 0x4000u

typedef __attribute__((ext_vector_type(8))) short bf16x8;
typedef __attribute__((ext_vector_type(4))) float f32x4;
typedef __attribute__((ext_vector_type(4))) unsigned int u32x4;
typedef __attribute__((ext_vector_type(2))) float f32x2;

__device__ inline unsigned short f2bf(float f) {
  unsigned u = __float_as_uint(f);
  unsigned r = (u + 0x7FFFu + ((u >> 16) & 1u)) >> 16;
  return (unsigned short)r;
}
__device__ inline float bfbits2f(unsigned u16) { return __uint_as_float(u16 << 16); }

// ---------------------------------------------------------------------------
__global__ __launch_bounds__(256) void cvt_bf16_k(const float* __restrict__ in,
                                                  unsigned short* __restrict__ out) {
  size_t t = (size_t)blockIdx.x * 256 + threadIdx.x;
  const float4* i4 = (const float4*)in;
  float4 a = i4[t * 2], b = i4[t * 2 + 1];
  ushort4 lo = make_ushort4(f2bf(a.x), f2bf(a.y), f2bf(a.z), f2bf(a.w));
  ushort4 hi = make_ushort4(f2bf(b.x), f2bf(b.y), f2bf(b.z), f2bf(b.w));
  ((ushort4*)out)[t * 2] = lo;
  ((ushort4*)out)[t * 2 + 1] = hi;
}

// ---------------------------------------------------------------------------
__global__ __launch_bounds__(256) void beta_k(const float* __restrict__ W_enc,
                                              const float* __restrict__ b_enc,
                                              const float* __restrict__ dec_bias,
                                              float* __restrict__ beta) {
  int f = blockIdx.x * 4 + (threadIdx.x >> 6);
  int lane = threadIdx.x & 63;
  const float* wr = W_enc + (size_t)f * ND;
  float s = 0.f;
  for (int d = lane; d < ND; d += 64) s += dec_bias[d] * wr[d];
  for (int off = 32; off; off >>= 1) s += __shfl_down(s, off);
  if (lane == 0) beta[f] = b_enc[f] - s;
}

// ---------------------------------------------------------------------------
__global__ __launch_bounds__(256) void transpose_bf_k(const float* __restrict__ in,
                                                      unsigned short* __restrict__ out) {
  __shared__ float tile[32][33];
  int lx = threadIdx.x & 31;
  int ty = threadIdx.x >> 5;
  int x = blockIdx.x * 32 + lx;  // f
  for (int j = ty; j < 32; j += 8) {
    int y = blockIdx.y * 32 + j;  // d
    tile[j][lx] = in[(size_t)y * NF + x];
  }
  __syncthreads();
  int xo = blockIdx.y * 32 + lx;  // d
  for (int j = ty; j < 32; j += 8) {
    int yo = blockIdx.x * 32 + j;  // f
    out[(size_t)yo * ND + xo] = f2bf(tile[lx][j]);
  }
}

// ---------------------------------------------------------------------------
// bf16 MFMA GEMM v7:
//  - 2-phase double-buffered LDS pipeline (stage next-tile BEFORE compute,
//    ONE barrier per K-step) -> load latency hidden under MFMA
//  - NO acts / tmax output: only glist candidate segments (epilogue-ectomy)
//  - candidates appended from acc registers via per-row LDS segments
__global__ __launch_bounds__(256) void enc_gemm_bf16(
    const unsigned short* __restrict__ Xb, const unsigned short* __restrict__ Wb,
    const float* __restrict__ beta, unsigned* __restrict__ glist) {
  __shared__ __align__(1024) unsigned short As[2][128 * 64];  // 32 KB
  __shared__ __align__(1024) unsigned short Bs[2][128 * 64];  // 32 KB
  __shared__ unsigned wseg[128][SEGW];                        // 8 KB
  __shared__ unsigned wcnt[128];                              // 0.5 KB
  const int tid = threadIdx.x;
  const int wave = tid >> 6, lane = tid & 63;
  const int wm = wave >> 1, wn = wave & 1;

  const int orig = blockIdx.y * gridDim.x + blockIdx.x;  // 0..8191
  const int xcd = orig & 7;
  const int local = orig >> 3;
  const int tcol = local >> 4;          // 0..63
  const int trow = (xcd << 4) + (local & 15);
  const int brow = trow << 7;
  const int bcol = tcol << 7;

  f32x4 acc[4][4] = {};

  const int srow = tid >> 3;                                   // 0..31
  const int scol = (((tid & 7) ^ ((tid >> 3) & 7)) << 3);      // pre-swizzled source chunk
  const unsigned short* gA = Xb + (size_t)(brow + srow) * ND + scol;
  const unsigned short* gB = Wb + (size_t)(bcol + srow) * ND + scol;

  // zero candidate segments (visible after first barrier)
#pragma unroll
  for (int i = 0; i < 8; ++i) ((unsigned*)wseg)[tid + 256 * i] = 0u;
  if (tid < 128) wcnt[tid] = 0u;

#define STAGE(bufsel, kt)                                                      \
  _Pragma("unroll")                                                            \
  for (int i = 0; i < 4; ++i) {                                                \
    __builtin_amdgcn_global_load_lds(                                          \
        (const __attribute__((address_space(1))) void*)(gA + (size_t)(i * 32) * ND + (kt)), \
        (__attribute__((address_space(3))) void*)(As[bufsel] + (i * 32 + wave * 8) * 64), 16, 0, 0); \
    __builtin_amdgcn_global_load_lds(                                          \
        (const __attribute__((address_space(1))) void*)(gB + (size_t)(i * 32) * ND + (kt)), \
        (__attribute__((address_space(3))) void*)(Bs[bufsel] + (i * 32 + wave * 8) * 64), 16, 0, 0); \
  }

  STAGE(0, 0)
  __syncthreads();
  int cur = 0;
#pragma unroll 1
  for (int step = 0; step < 12; ++step) {
    if (step < 11) { STAGE(cur ^ 1, (step + 1) * 64) }
#pragma unroll
    for (int kk = 0; kk < 64; kk += 32) {
      const int chunk = (kk + ((lane >> 4) << 3)) >> 3;  // 0..7 (16B units)
      const int rA = (wm << 6) + (lane & 15);
      const int rB = (wn << 6) + (lane & 15);
      const int sw = chunk ^ (lane & 7);
      bf16x8 a[4], bvv[4];
#pragma unroll
      for (int m = 0; m < 4; ++m)
        a[m] = *(const bf16x8*)&As[cur][(rA + (m << 4)) * 64 + (sw << 3)];
#pragma unroll
      for (int n = 0; n < 4; ++n)
        bvv[n] = *(const bf16x8*)&Bs[cur][(rB + (n << 4)) * 64 + (sw << 3)];
#pragma unroll
      for (int m = 0; m < 4; ++m)
#pragma unroll
        for (int n = 0; n < 4; ++n)
          acc[m][n] = __builtin_amdgcn_mfma_f32_16x16x32_bf16(a[m], bvv[n], acc[m][n], 0, 0, 0);
    }
    if (step < 11) {
      __syncthreads();
      cur ^= 1;
    }
  }

  // ---- epilogue: candidate append straight from acc (no acts write)
#pragma unroll
  for (int n = 0; n < 4; ++n) {
    float bet = beta[bcol + (wn << 6) + (n << 4) + (lane & 15)];
#pragma unroll
    for (int m = 0; m < 4; ++m) {
#pragma unroll
      for (int r = 0; r < 4; ++r) {
        int row_l = (wm << 6) + (m << 4) + ((lane >> 4) << 2) + r;
        int col_l = (wn << 6) + (n << 4) + (lane & 15);
        float v = fmaxf(acc[m][n][r] + bet, 0.f);
        unsigned short ub = f2bf(v);
        if (ub >= (unsigned short)THETA0_BITS) {
          unsigned p = atomicAdd(&wcnt[row_l], 1u);
          if (p < SEGW) wseg[row_l][p] = ((unsigned)ub << 16) | (unsigned)(bcol + col_l);
        }
      }
    }
  }
  __syncthreads();
  // flush: thread tid covers row tid>>1, slots ((tid&1)*8 .. +8)
  {
    int row = tid >> 1;
    int sbase = (tid & 1) << 3;
    u32x4 v0 = *(const u32x4*)&wseg[row][sbase];
    u32x4 v1 = *(const u32x4*)&wseg[row][sbase + 4];
    if (sbase == 0 && wcnt[row] > SEGW) v0[0] = 0xFFFFFFFFu;  // overflow sentinel
    unsigned* dst = &glist[(size_t)(brow + row) * GSEG + (tcol << 4)];
    __builtin_nontemporal_store(v0, (u32x4*)&dst[sbase]);
    __builtin_nontemporal_store(v1, (u32x4*)&dst[sbase + 4]);
  }
}

// ---------------------------------------------------------------------------
// ksel v7: wave-per-row fast path on GEMM-built segments (4 KB/row).
// Invalid (sentinel / n<k / tau<THETA0+MARG, P~1e-3 per launch) -> block-
// cooperative EXACT fp32 recompute of the row (deterministic, reference
// selection semantics). No acts/tmax dependency at all.
__global__ __launch_bounds__(256, 6) void ksel_k(
    const unsigned* __restrict__ glist,
    const float* __restrict__ x, const float* __restrict__ W_enc,
    const float* __restrict__ beta, const unsigned short* __restrict__ WdecBf,
    const float* __restrict__ dec_bias, const int* __restrict__ kptr,
    float* __restrict__ out_rec, float* __restrict__ g_vals, int* __restrict__ g_idxs) {
  const int tid = threadIdx.x, wave = tid >> 6, lane = tid & 63;
  const int b = blockIdx.x * 4 + wave;
  int k = *kptr; k = k < 1 ? 1 : (k > 64 ? 64 : k);
  const unsigned kk = (unsigned)k;

  __shared__ unsigned clist_s[4][CMAX];
  __shared__ unsigned long long aval_s[4][AMAX];
  __shared__ float selv_s[4][64];
  __shared__ int seli_s[4][64];
  __shared__ int ctrC_s[4], ctrW_s[4], ctrA_s[4];
  __shared__ int blkFb;
  // fallback scratch
  __shared__ float fb_x[ND];
  __shared__ unsigned long long fbl[512];
  __shared__ unsigned fb_thrmax[256];
  __shared__ unsigned long long fb_red[4];
  __shared__ unsigned fb_cnt4[4];
  __shared__ unsigned fbcnt;

  unsigned* clist = clist_s[wave];
  unsigned long long* aval = aval_s[wave];
  float* selv = selv_s[wave];
  int* seli = seli_s[wave];

  if (tid == 0) blkFb = 0;
  if (lane == 0) { ctrC_s[wave] = 0; ctrW_s[wave] = 0; ctrA_s[wave] = 0; }

  // ---- fast path: load + compact the segmented list (4 KB/row)
  bool bad = false;
  {
    const u32x4* seg4 = (const u32x4*)(glist + (size_t)b * GSEG);
#pragma unroll
    for (int ii = 0; ii < 4; ++ii) {
      u32x4 e4 = __builtin_nontemporal_load(&seg4[lane + (ii << 6)]);
#pragma unroll
      for (int q = 0; q < 4; ++q) {
        unsigned e = e4[q];
        if (e) {
          if ((e & 0xFFFFu) >= (unsigned)NF) bad = true;  // sentinel
          else {
            int p = atomicAdd(&ctrC_s[wave], 1);
            if (p < CMAX) clist[p] = e;
          }
        }
      }
    }
  }
  bad = (__ballot(bad) != 0ull);
  int n = ctrC_s[wave]; if (n > CMAX) n = CMAX;

  // tau via 15-probe bitwise binary search over the list
  unsigned ks[8];
#pragma unroll
  for (int ii = 0; ii < 8; ++ii) {
    int j = lane + (ii << 6);
    ks[ii] = (j < n) ? (clist[j] >> 16) : 0u;
  }
  unsigned T = 0;
  for (int bit = 14; bit >= 0; --bit) {
    unsigned probe = T | (1u << bit);
    int c = 0;
#pragma unroll
    for (int ii = 0; ii < 8; ++ii) c += (ks[ii] >= probe);
#pragma unroll
    for (int off = 32; off; off >>= 1) c += __shfl_xor(c, off);
    if (c >= (int)kk) T = probe;
  }
  float tauf = bfbits2f(T);

  bool valid = !bad && (n >= k) && (tauf >= THETA0 + MARG);
  if (lane == 0 && !valid) atomicOr(&blkFb, 1);
  __syncthreads();

  if (!blkFb) {
    // ---- classify: winners (bf16 value final) / ambiguous band
    const float thrW = tauf + MARG;
    const float thrA = tauf - MARG;
    for (int j = lane; j < n; j += 64) {
      unsigned e = clist[j];
      float v = bfbits2f(e >> 16);
      int idx = (int)(e & 0xFFFFu);
      if (v > thrW) {
        int p = atomicAdd(&ctrW_s[wave], 1);
        if (p < 63) { selv[p] = v; seli[p] = idx; }  // count(v > tau) <= k-1
      } else if (v >= thrA) {
        int p = atomicAdd(&ctrA_s[wave], 1);
        if (p < AMAX) aval[p] = (unsigned long long)(unsigned)idx;
      }
    }
    __syncthreads();
    int c = ctrW_s[wave]; if (c > 63) c = 63; if (c > k - 1) c = k - 1;
    int na = ctrA_s[wave]; if (na > AMAX) na = AMAX;

    // exact fp32 dots for ambiguous (2-wide)
    float xr[12];
#pragma unroll
    for (int cc = 0; cc < 12; ++cc)
      xr[cc] = __builtin_nontemporal_load(&x[(size_t)b * ND + lane + 64 * cc]);
    for (int j = 0; j < na; j += 2) {
      int f0 = (int)(unsigned)aval[j];
      int f1 = (j + 1 < na) ? (int)(unsigned)aval[j + 1] : f0;
      const float* w0 = W_enc + (size_t)f0 * ND;
      const float* w1 = W_enc + (size_t)f1 * ND;
      float s0 = 0.f, s1 = 0.f;
#pragma unroll
      for (int cc = 0; cc < 12; ++cc) {
        s0 = fmaf(xr[cc], w0[lane + 64 * cc], s0);
        s1 = fmaf(xr[cc], w1[lane + 64 * cc], s1);
      }
#pragma unroll
      for (int off = 32; off; off >>= 1) {
        s0 += __shfl_xor(s0, off);
        s1 += __shfl_xor(s1, off);
      }
      if (lane == 0) {
        float v0 = fmaxf(s0 + beta[f0], 0.f);
        aval[j] = (((unsigned long long)__float_as_uint(v0)) << 13) | (unsigned)(8191 - f0);
        if (j + 1 < na) {
          float v1 = fmaxf(s1 + beta[f1], 0.f);
          aval[j + 1] = (((unsigned long long)__float_as_uint(v1)) << 13) | (unsigned)(8191 - f1);
        }
      }
    }
    __syncthreads();

    // select top (k-c) ambiguous by (exact val desc, idx asc)
    unsigned long long p0 = (lane < na) ? aval[lane] : 0ull;
    unsigned long long p1 = (lane + 64 < na) ? aval[lane + 64] : 0ull;
    int rounds = k - c; if (rounds < 0) rounds = 0;
    for (int r = 0; r < rounds; ++r) {
      unsigned long long m = p0 > p1 ? p0 : p1;
#pragma unroll
      for (int off = 32; off; off >>= 1) {
        unsigned long long o = __shfl_xor(m, off);
        if (o > m) m = o;
      }
      if (lane == 0) {
        if (m) { selv[c + r] = __uint_as_float((unsigned)(m >> 13)); seli[c + r] = 8191 - (int)(m & 0x1FFFull); }
        else   { selv[c + r] = 0.f; seli[c + r] = 0; }
      }
      if (p0 == m) p0 = 0;
      if (p1 == m) p1 = 0;
    }
    __syncthreads();
  } else {
    // ---- fallback: block-cooperative exact fp32 recompute, rows sequential
    for (int r = 0; r < 4; ++r) {
      const int row = blockIdx.x * 4 + r;
      fb_x[tid] = x[(size_t)row * ND + tid];
      fb_x[tid + 256] = x[(size_t)row * ND + tid + 256];
      fb_x[tid + 512] = x[(size_t)row * ND + tid + 512];
      __syncthreads();
      // sweep 1: 32 features/thread, track per-thread max (fp32 bits, relu'd)
      unsigned mymax = 0u;
      for (int j = 0; j < 32; ++j) {
        int f = tid * 32 + j;
        const float* w = W_enc + (size_t)f * ND;
        float s = 0.f;
#pragma unroll 8
        for (int d = 0; d < ND; ++d) s = fmaf(fb_x[d], w[d], s);
        unsigned bits = __float_as_uint(fmaxf(s + beta[f], 0.f));
        if (bits > mymax) mymax = bits;
      }
      fb_thrmax[tid] = mymax;
      __syncthreads();
      // L = k-th largest thread-max (<= tau, guarantees >= k candidates)
      unsigned L = 0;
      for (int bit = 30; bit >= 0; --bit) {
        unsigned probe = L | (1u << bit);
        unsigned long long bl = __ballot(fb_thrmax[tid] >= probe);
        if (lane == 0) fb_cnt4[wave] = (unsigned)__popcll(bl);
        __syncthreads();
        unsigned tot = fb_cnt4[0] + fb_cnt4[1] + fb_cnt4[2] + fb_cnt4[3];
        if (tot >= kk) L = probe;
        __syncthreads();
      }
      if (tid == 0) fbcnt = 0u;
      __syncthreads();
      // sweep 2: append candidates (bits >= L)
      for (int j = 0; j < 32; ++j) {
        int f = tid * 32 + j;
        const float* w = W_enc + (size_t)f * ND;
        float s = 0.f;
#pragma unroll 8
        for (int d = 0; d < ND; ++d) s = fmaf(fb_x[d], w[d], s);
        unsigned bits = __float_as_uint(fmaxf(s + beta[f], 0.f));
        if (bits >= L) {
          unsigned p = atomicAdd(&fbcnt, 1u);
          if (p < 512) fbl[p] = (((unsigned long long)bits) << 13) | (unsigned)(8191 - f);
        }
      }
      __syncthreads();
      int n2 = (int)(fbcnt < 512u ? fbcnt : 512u);
      // k rounds of block-wide argmax (val desc, idx asc)
      for (int rr = 0; rr < k; ++rr) {
        unsigned long long best = 0ull;
        for (int j2 = tid; j2 < n2; j2 += 256)
          if (fbl[j2] > best) best = fbl[j2];
#pragma unroll
        for (int off = 32; off; off >>= 1) {
          unsigned long long o = __shfl_xor(best, off);
          if (o > best) best = o;
        }
        if (lane == 0) fb_red[wave] = best;
        __syncthreads();
        unsigned long long m = fb_red[0];
#pragma unroll
        for (int w2 = 1; w2 < 4; ++w2)
          if (fb_red[w2] > m) m = fb_red[w2];
        if (tid == 0) {
          if (m) { selv_s[r][rr] = __uint_as_float((unsigned)(m >> 13)); seli_s[r][rr] = 8191 - (int)(m & 0x1FFFull); }
          else   { selv_s[r][rr] = 0.f; seli_s[r][rr] = 0; }
        }
        for (int j2 = tid; j2 < n2; j2 += 256)
          if (fbl[j2] == m) fbl[j2] = 0ull;
        __syncthreads();
      }
      __syncthreads();
    }
  }

  if (lane < k) {
    g_vals[(size_t)b * 64 + lane] = selv[lane];
    g_idxs[(size_t)b * 64 + lane] = seli[lane];
  }

  // ---- fused reconstruction (bf16 decoder gathers, cached)
  float acc[12];
#pragma unroll
  for (int cc = 0; cc < 6; ++cc) {
    float2 db = *(const float2*)&dec_bias[cc * 128 + lane * 2];
    acc[2 * cc] = db.x; acc[2 * cc + 1] = db.y;
  }
#define RECON_TERM(r)                                                          \
  {                                                                            \
    int f = seli[r]; float v = selv[r];                                        \
    const unsigned short* wd = WdecBf + (size_t)f * ND;                        \
    _Pragma("unroll")                                                          \
    for (int cc = 0; cc < 6; ++cc) {                                           \
      unsigned pr = *(const unsigned*)&wd[cc * 128 + lane * 2];                \
      acc[2 * cc] = fmaf(v, bfbits2f(pr & 0xFFFFu), acc[2 * cc]);              \
      acc[2 * cc + 1] = fmaf(v, bfbits2f(pr >> 16), acc[2 * cc + 1]);          \
    }                                                                          \
  }
  if (k == 32) {
#pragma unroll
    for (int r = 0; r < 32; ++r) RECON_TERM(r)
  } else {
    for (int r = 0; r < k; ++r) RECON_TERM(r)
  }
#pragma unroll
  for (int cc = 0; cc < 6; ++cc) {
    f32x2 st = {acc[2 * cc], acc[2 * cc + 1]};
    __builtin_nontemporal_store(st, (f32x2*)&out_rec[(size_t)b * ND + cc * 128 + lane * 2]);
  }
}

// ---------------------------------------------------------------------------
__global__ __launch_bounds__(256) void d2_sparse_k(
    const float* __restrict__ g_vals, const int* __restrict__ g_idxs,
    const int* __restrict__ kptr, float* __restrict__ out_sc) {
  const int b = blockIdx.x, tid = threadIdx.x;
  int k = *kptr; k = k < 1 ? 1 : (k > 64 ? 64 : k);
  __shared__ float row[NF];
  __shared__ float sv[64];
  __shared__ int si[64];
  if (tid < k) { sv[tid] = g_vals[(size_t)b * 64 + tid]; si[tid] = g_idxs[(size_t)b * 64 + tid]; }
  float4* r4 = (float4*)row;
#pragma unroll
  for (int i = 0; i < 8; ++i) r4[tid + 256 * i] = make_float4(0.f, 0.f, 0.f, 0.f);
  __syncthreads();
  if (tid < k) row[si[tid]] = sv[tid];
  __syncthreads();
  f32x4* o4 = (f32x4*)(out_sc + (size_t)b * NF);
  const f32x4* r4v = (const f32x4*)row;
#pragma unroll
  for (int i = 0; i < 8; ++i)
    __builtin_nontemporal_store(r4v[tid + 256 * i], &o4[tid + 256 * i]);
}

// ---------------------------------------------------------------------------
extern "C" void kernel_launch(void* const* d_in, const int* in_sizes, int n_in,
                              void* d_out, int out_size, void* d_ws, size_t ws_size,
                              hipStream_t stream) {
  const float* x        = (const float*)d_in[0];
  const float* W_enc    = (const float*)d_in[1];
  const float* b_enc    = (const float*)d_in[2];
  const float* W_dec    = (const float*)d_in[3];
  const float* dec_bias = (const float*)d_in[4];
  const int*   kptr     = (const int*)d_in[5];

  float* out_rec = (float*)d_out;
  float* out_sc  = (float*)d_out + (size_t)NB * ND;

  // scratch carved from the sparse-code output region (rewritten by d2 last)
  char* scb = (char*)out_sc;
  unsigned*       glist = (unsigned*)scb;                      // 64 MB
  unsigned short* Xbf   = (unsigned short*)(scb + 67108864);   // 24 MB
  unsigned short* Wbf   = (unsigned short*)(scb + 92274688);   // 12 MB

  char* ws = (char*)d_ws;
  unsigned short* WdecBf = (unsigned short*)ws;        // 12,582,912 B
  float* beta   = (float*)(ws + 12582912);             //     32,768 B
  float* g_vals = (float*)(ws + 12615680);             //  4,194,304 B
  int*   g_idxs = (int*)(ws + 16809984);               //  4,194,304 B

  cvt_bf16_k<<<(NB * ND) / 2048, 256, 0, stream>>>(x, Xbf);
  cvt_bf16_k<<<(NF * ND) / 2048, 256, 0, stream>>>(W_enc, Wbf);
  beta_k<<<NF / 4, 256, 0, stream>>>(W_enc, b_enc, dec_bias, beta);
  transpose_bf_k<<<dim3(NF / 32, ND / 32), 256, 0, stream>>>(W_dec, WdecBf);
  enc_gemm_bf16<<<dim3(NF / 128, NB / 128), 256, 0, stream>>>(Xbf, Wbf, beta, glist);
  ksel_k<<<NB / 4, 256, 0, stream>>>(glist, x, W_enc, beta, WdecBf, dec_bias, kptr,
                                     out_rec, g_vals, g_idxs);
  d2_sparse_k<<<NB, 256, 0, stream>>>(g_vals, g_idxs, kptr, out_sc);
}

// Round 13
// 571.779 us; speedup vs baseline: 1.6455x; 1.1314x over previous
//
#include <hip/hip_runtime.h>

#define NB 16384
#define ND 768
#define NF 8192
#define CMAX 512        // ksel compact list cap per row
#define SEGW 16         // glist slots per (row,tile) segment
#define GSEG 1024       // glist u32 per row (64 tiles x 16 slots)
#define AMAX 128        // ambiguous cap per row (expect ~13)
#define MARG 0.07f      // classification margin (>= 2x bf16-GEMM act error bound)
#define THETA0 2.0f     // GEMM-side candidate threshold (bf16-exact)
#define THETA0_BITS 0x4000u

typedef __attribute__((ext_vector_type(8))) short bf16x8;
typedef __attribute__((ext_vector_type(4))) float f32x4;
typedef __attribute__((ext_vector_type(4))) unsigned int u32x4;
typedef __attribute__((ext_vector_type(2))) float f32x2;

__device__ inline unsigned short f2bf(float f) {
  unsigned u = __float_as_uint(f);
  unsigned r = (u + 0x7FFFu + ((u >> 16) & 1u)) >> 16;
  return (unsigned short)r;
}
__device__ inline float bfbits2f(unsigned u16) { return __uint_as_float(u16 << 16); }

// ---------------------------------------------------------------------------
__global__ __launch_bounds__(256) void cvt_bf16_k(const float* __restrict__ in,
                                                  unsigned short* __restrict__ out) {
  size_t t = (size_t)blockIdx.x * 256 + threadIdx.x;
  const float4* i4 = (const float4*)in;
  float4 a = i4[t * 2], b = i4[t * 2 + 1];
  ushort4 lo = make_ushort4(f2bf(a.x), f2bf(a.y), f2bf(a.z), f2bf(a.w));
  ushort4 hi = make_ushort4(f2bf(b.x), f2bf(b.y), f2bf(b.z), f2bf(b.w));
  ((ushort4*)out)[t * 2] = lo;
  ((ushort4*)out)[t * 2 + 1] = hi;
}

// ---------------------------------------------------------------------------
__global__ __launch_bounds__(256) void beta_k(const float* __restrict__ W_enc,
                                              const float* __restrict__ b_enc,
                                              const float* __restrict__ dec_bias,
                                              float* __restrict__ beta) {
  int f = blockIdx.x * 4 + (threadIdx.x >> 6);
  int lane = threadIdx.x & 63;
  const float* wr = W_enc + (size_t)f * ND;
  float s = 0.f;
  for (int d = lane; d < ND; d += 64) s += dec_bias[d] * wr[d];
  for (int off = 32; off; off >>= 1) s += __shfl_down(s, off);
  if (lane == 0) beta[f] = b_enc[f] - s;
}

// ---------------------------------------------------------------------------
__global__ __launch_bounds__(256) void transpose_bf_k(const float* __restrict__ in,
                                                      unsigned short* __restrict__ out) {
  __shared__ float tile[32][33];
  int lx = threadIdx.x & 31;
  int ty = threadIdx.x >> 5;
  int x = blockIdx.x * 32 + lx;  // f
  for (int j = ty; j < 32; j += 8) {
    int y = blockIdx.y * 32 + j;  // d
    tile[j][lx] = in[(size_t)y * NF + x];
  }
  __syncthreads();
  int xo = blockIdx.y * 32 + lx;  // d
  for (int j = ty; j < 32; j += 8) {
    int yo = blockIdx.x * 32 + j;  // f
    out[(size_t)yo * ND + xo] = f2bf(tile[lx][j]);
  }
}

// ---------------------------------------------------------------------------
// bf16 MFMA GEMM v8: single-buffered staging (32 KB LDS -> 4 blocks/CU for
// inter-block latency hiding, m97/m114 mechanism), epilogue-ectomy kept,
// candidate segments overlaid on the dead As buffer after the K-loop.
__global__ __launch_bounds__(256) void enc_gemm_bf16(
    const unsigned short* __restrict__ Xb, const unsigned short* __restrict__ Wb,
    const float* __restrict__ beta, unsigned* __restrict__ glist) {
  __shared__ __align__(1024) unsigned short As[128 * 64];  // 16 KB
  __shared__ __align__(1024) unsigned short Bs[128 * 64];  // 16 KB
  const int tid = threadIdx.x;
  const int wave = tid >> 6, lane = tid & 63;
  const int wm = wave >> 1, wn = wave & 1;

  const int orig = blockIdx.y * gridDim.x + blockIdx.x;  // 0..8191
  const int xcd = orig & 7;
  const int local = orig >> 3;
  const int tcol = local >> 4;          // 0..63
  const int trow = (xcd << 4) + (local & 15);
  const int brow = trow << 7;
  const int bcol = tcol << 7;

  f32x4 acc[4][4] = {};

  const int srow = tid >> 3;                                   // 0..31
  const int scol = (((tid & 7) ^ ((tid >> 3) & 7)) << 3);      // pre-swizzled source chunk
  const unsigned short* gA = Xb + (size_t)(brow + srow) * ND + scol;
  const unsigned short* gB = Wb + (size_t)(bcol + srow) * ND + scol;

#pragma unroll 1
  for (int step = 0; step < 12; ++step) {
    const int kt = step * 64;
#pragma unroll
    for (int i = 0; i < 4; ++i) {
      __builtin_amdgcn_global_load_lds(
          (const __attribute__((address_space(1))) void*)(gA + (size_t)(i * 32) * ND + kt),
          (__attribute__((address_space(3))) void*)(As + (i * 32 + wave * 8) * 64), 16, 0, 0);
      __builtin_amdgcn_global_load_lds(
          (const __attribute__((address_space(1))) void*)(gB + (size_t)(i * 32) * ND + kt),
          (__attribute__((address_space(3))) void*)(Bs + (i * 32 + wave * 8) * 64), 16, 0, 0);
    }
    __syncthreads();
#pragma unroll
    for (int kk = 0; kk < 64; kk += 32) {
      const int chunk = (kk + ((lane >> 4) << 3)) >> 3;  // 0..7 (16B units)
      const int rA = (wm << 6) + (lane & 15);
      const int rB = (wn << 6) + (lane & 15);
      const int sw = chunk ^ (lane & 7);
      bf16x8 a[4], bvv[4];
#pragma unroll
      for (int m = 0; m < 4; ++m)
        a[m] = *(const bf16x8*)&As[(rA + (m << 4)) * 64 + (sw << 3)];
#pragma unroll
      for (int n = 0; n < 4; ++n)
        bvv[n] = *(const bf16x8*)&Bs[(rB + (n << 4)) * 64 + (sw << 3)];
#pragma unroll
      for (int m = 0; m < 4; ++m)
#pragma unroll
        for (int n = 0; n < 4; ++n)
          acc[m][n] = __builtin_amdgcn_mfma_f32_16x16x32_bf16(a[m], bvv[n], acc[m][n], 0, 0, 0);
    }
    __syncthreads();
  }

  // ---- epilogue: overlay candidate segments on the (now dead) As buffer
  unsigned (*wseg)[SEGW] = (unsigned (*)[SEGW])As;        // 128 x 16 u32 = 8 KB
  unsigned* wcnt = (unsigned*)(As + 4096);                // 512 B (byte off 8 KB)
#pragma unroll
  for (int i = 0; i < 8; ++i) ((unsigned*)wseg)[tid + 256 * i] = 0u;
  if (tid < 128) wcnt[tid] = 0u;
  __syncthreads();

#pragma unroll
  for (int n = 0; n < 4; ++n) {
    float bet = beta[bcol + (wn << 6) + (n << 4) + (lane & 15)];
#pragma unroll
    for (int m = 0; m < 4; ++m) {
#pragma unroll
      for (int r = 0; r < 4; ++r) {
        int row_l = (wm << 6) + (m << 4) + ((lane >> 4) << 2) + r;
        int col_l = (wn << 6) + (n << 4) + (lane & 15);
        float v = fmaxf(acc[m][n][r] + bet, 0.f);
        unsigned short ub = f2bf(v);
        if (ub >= (unsigned short)THETA0_BITS) {
          unsigned p = atomicAdd(&wcnt[row_l], 1u);
          if (p < SEGW) wseg[row_l][p] = ((unsigned)ub << 16) | (unsigned)(bcol + col_l);
        }
      }
    }
  }
  __syncthreads();
  // flush: thread tid covers row tid>>1, slots ((tid&1)*8 .. +8)
  {
    int row = tid >> 1;
    int sbase = (tid & 1) << 3;
    u32x4 v0 = *(const u32x4*)&wseg[row][sbase];
    u32x4 v1 = *(const u32x4*)&wseg[row][sbase + 4];
    if (sbase == 0 && wcnt[row] > SEGW) v0[0] = 0xFFFFFFFFu;  // overflow sentinel
    unsigned* dst = &glist[(size_t)(brow + row) * GSEG + (tcol << 4)];
    __builtin_nontemporal_store(v0, (u32x4*)&dst[sbase]);
    __builtin_nontemporal_store(v1, (u32x4*)&dst[sbase + 4]);
  }
}

// ---------------------------------------------------------------------------
// ksel v7 (unchanged): wave-per-row fast path on GEMM-built segments.
// Invalid (sentinel / n<k / tau<THETA0+MARG, P~1e-3 per launch) -> block-
// cooperative EXACT fp32 recompute of the rows (deterministic).
__global__ __launch_bounds__(256, 6) void ksel_k(
    const unsigned* __restrict__ glist,
    const float* __restrict__ x, const float* __restrict__ W_enc,
    const float* __restrict__ beta, const unsigned short* __restrict__ WdecBf,
    const float* __restrict__ dec_bias, const int* __restrict__ kptr,
    float* __restrict__ out_rec, float* __restrict__ g_vals, int* __restrict__ g_idxs) {
  const int tid = threadIdx.x, wave = tid >> 6, lane = tid & 63;
  const int b = blockIdx.x * 4 + wave;
  int k = *kptr; k = k < 1 ? 1 : (k > 64 ? 64 : k);
  const unsigned kk = (unsigned)k;

  __shared__ unsigned clist_s[4][CMAX];
  __shared__ unsigned long long aval_s[4][AMAX];
  __shared__ float selv_s[4][64];
  __shared__ int seli_s[4][64];
  __shared__ int ctrC_s[4], ctrW_s[4], ctrA_s[4];
  __shared__ int blkFb;
  __shared__ float fb_x[ND];
  __shared__ unsigned long long fbl[512];
  __shared__ unsigned fb_thrmax[256];
  __shared__ unsigned long long fb_red[4];
  __shared__ unsigned fb_cnt4[4];
  __shared__ unsigned fbcnt;

  unsigned* clist = clist_s[wave];
  unsigned long long* aval = aval_s[wave];
  float* selv = selv_s[wave];
  int* seli = seli_s[wave];

  if (tid == 0) blkFb = 0;
  if (lane == 0) { ctrC_s[wave] = 0; ctrW_s[wave] = 0; ctrA_s[wave] = 0; }

  // ---- fast path: load + compact the segmented list (4 KB/row)
  bool bad = false;
  {
    const u32x4* seg4 = (const u32x4*)(glist + (size_t)b * GSEG);
#pragma unroll
    for (int ii = 0; ii < 4; ++ii) {
      u32x4 e4 = __builtin_nontemporal_load(&seg4[lane + (ii << 6)]);
#pragma unroll
      for (int q = 0; q < 4; ++q) {
        unsigned e = e4[q];
        if (e) {
          if ((e & 0xFFFFu) >= (unsigned)NF) bad = true;  // sentinel
          else {
            int p = atomicAdd(&ctrC_s[wave], 1);
            if (p < CMAX) clist[p] = e;
          }
        }
      }
    }
  }
  bad = (__ballot(bad) != 0ull);
  int n = ctrC_s[wave]; if (n > CMAX) n = CMAX;

  // tau via 15-probe bitwise binary search over the list
  unsigned ks[8];
#pragma unroll
  for (int ii = 0; ii < 8; ++ii) {
    int j = lane + (ii << 6);
    ks[ii] = (j < n) ? (clist[j] >> 16) : 0u;
  }
  unsigned T = 0;
  for (int bit = 14; bit >= 0; --bit) {
    unsigned probe = T | (1u << bit);
    int c = 0;
#pragma unroll
    for (int ii = 0; ii < 8; ++ii) c += (ks[ii] >= probe);
#pragma unroll
    for (int off = 32; off; off >>= 1) c += __shfl_xor(c, off);
    if (c >= (int)kk) T = probe;
  }
  float tauf = bfbits2f(T);

  bool valid = !bad && (n >= k) && (tauf >= THETA0 + MARG);
  if (lane == 0 && !valid) atomicOr(&blkFb, 1);
  __syncthreads();

  if (!blkFb) {
    const float thrW = tauf + MARG;
    const float thrA = tauf - MARG;
    for (int j = lane; j < n; j += 64) {
      unsigned e = clist[j];
      float v = bfbits2f(e >> 16);
      int idx = (int)(e & 0xFFFFu);
      if (v > thrW) {
        int p = atomicAdd(&ctrW_s[wave], 1);
        if (p < 63) { selv[p] = v; seli[p] = idx; }
      } else if (v >= thrA) {
        int p = atomicAdd(&ctrA_s[wave], 1);
        if (p < AMAX) aval[p] = (unsigned long long)(unsigned)idx;
      }
    }
    __syncthreads();
    int c = ctrW_s[wave]; if (c > 63) c = 63; if (c > k - 1) c = k - 1;
    int na = ctrA_s[wave]; if (na > AMAX) na = AMAX;

    float xr[12];
#pragma unroll
    for (int cc = 0; cc < 12; ++cc)
      xr[cc] = __builtin_nontemporal_load(&x[(size_t)b * ND + lane + 64 * cc]);
    for (int j = 0; j < na; j += 2) {
      int f0 = (int)(unsigned)aval[j];
      int f1 = (j + 1 < na) ? (int)(unsigned)aval[j + 1] : f0;
      const float* w0 = W_enc + (size_t)f0 * ND;
      const float* w1 = W_enc + (size_t)f1 * ND;
      float s0 = 0.f, s1 = 0.f;
#pragma unroll
      for (int cc = 0; cc < 12; ++cc) {
        s0 = fmaf(xr[cc], w0[lane + 64 * cc], s0);
        s1 = fmaf(xr[cc], w1[lane + 64 * cc], s1);
      }
#pragma unroll
      for (int off = 32; off; off >>= 1) {
        s0 += __shfl_xor(s0, off);
        s1 += __shfl_xor(s1, off);
      }
      if (lane == 0) {
        float v0 = fmaxf(s0 + beta[f0], 0.f);
        aval[j] = (((unsigned long long)__float_as_uint(v0)) << 13) | (unsigned)(8191 - f0);
        if (j + 1 < na) {
          float v1 = fmaxf(s1 + beta[f1], 0.f);
          aval[j + 1] = (((unsigned long long)__float_as_uint(v1)) << 13) | (unsigned)(8191 - f1);
        }
      }
    }
    __syncthreads();

    unsigned long long p0 = (lane < na) ? aval[lane] : 0ull;
    unsigned long long p1 = (lane + 64 < na) ? aval[lane + 64] : 0ull;
    int rounds = k - c; if (rounds < 0) rounds = 0;
    for (int r = 0; r < rounds; ++r) {
      unsigned long long m = p0 > p1 ? p0 : p1;
#pragma unroll
      for (int off = 32; off; off >>= 1) {
        unsigned long long o = __shfl_xor(m, off);
        if (o > m) m = o;
      }
      if (lane == 0) {
        if (m) { selv[c + r] = __uint_as_float((unsigned)(m >> 13)); seli[c + r] = 8191 - (int)(m & 0x1FFFull); }
        else   { selv[c + r] = 0.f; seli[c + r] = 0; }
      }
      if (p0 == m) p0 = 0;
      if (p1 == m) p1 = 0;
    }
    __syncthreads();
  } else {
    // ---- fallback: block-cooperative exact fp32 recompute, rows sequential
    for (int r = 0; r < 4; ++r) {
      const int row = blockIdx.x * 4 + r;
      fb_x[tid] = x[(size_t)row * ND + tid];
      fb_x[tid + 256] = x[(size_t)row * ND + tid + 256];
      fb_x[tid + 512] = x[(size_t)row * ND + tid + 512];
      __syncthreads();
      unsigned mymax = 0u;
      for (int j = 0; j < 32; ++j) {
        int f = tid * 32 + j;
        const float* w = W_enc + (size_t)f * ND;
        float s = 0.f;
#pragma unroll 8
        for (int d = 0; d < ND; ++d) s = fmaf(fb_x[d], w[d], s);
        unsigned bits = __float_as_uint(fmaxf(s + beta[f], 0.f));
        if (bits > mymax) mymax = bits;
      }
      fb_thrmax[tid] = mymax;
      __syncthreads();
      unsigned L = 0;
      for (int bit = 30; bit >= 0; --bit) {
        unsigned probe = L | (1u << bit);
        unsigned long long bl = __ballot(fb_thrmax[tid] >= probe);
        if (lane == 0) fb_cnt4[wave] = (unsigned)__popcll(bl);
        __syncthreads();
        unsigned tot = fb_cnt4[0] + fb_cnt4[1] + fb_cnt4[2] + fb_cnt4[3];
        if (tot >= kk) L = probe;
        __syncthreads();
      }
      if (tid == 0) fbcnt = 0u;
      __syncthreads();
      for (int j = 0; j < 32; ++j) {
        int f = tid * 32 + j;
        const float* w = W_enc + (size_t)f * ND;
        float s = 0.f;
#pragma unroll 8
        for (int d = 0; d < ND; ++d) s = fmaf(fb_x[d], w[d], s);
        unsigned bits = __float_as_uint(fmaxf(s + beta[f], 0.f));
        if (bits >= L) {
          unsigned p = atomicAdd(&fbcnt, 1u);
          if (p < 512) fbl[p] = (((unsigned long long)bits) << 13) | (unsigned)(8191 - f);
        }
      }
      __syncthreads();
      int n2 = (int)(fbcnt < 512u ? fbcnt : 512u);
      for (int rr = 0; rr < k; ++rr) {
        unsigned long long best = 0ull;
        for (int j2 = tid; j2 < n2; j2 += 256)
          if (fbl[j2] > best) best = fbl[j2];
#pragma unroll
        for (int off = 32; off; off >>= 1) {
          unsigned long long o = __shfl_xor(best, off);
          if (o > best) best = o;
        }
        if (lane == 0) fb_red[wave] = best;
        __syncthreads();
        unsigned long long m = fb_red[0];
#pragma unroll
        for (int w2 = 1; w2 < 4; ++w2)
          if (fb_red[w2] > m) m = fb_red[w2];
        if (tid == 0) {
          if (m) { selv_s[r][rr] = __uint_as_float((unsigned)(m >> 13)); seli_s[r][rr] = 8191 - (int)(m & 0x1FFFull); }
          else   { selv_s[r][rr] = 0.f; seli_s[r][rr] = 0; }
        }
        for (int j2 = tid; j2 < n2; j2 += 256)
          if (fbl[j2] == m) fbl[j2] = 0ull;
        __syncthreads();
      }
      __syncthreads();
    }
  }

  if (lane < k) {
    g_vals[(size_t)b * 64 + lane] = selv[lane];
    g_idxs[(size_t)b * 64 + lane] = seli[lane];
  }

  // ---- fused reconstruction (bf16 decoder gathers, cached)
  float acc[12];
#pragma unroll
  for (int cc = 0; cc < 6; ++cc) {
    float2 db = *(const float2*)&dec_bias[cc * 128 + lane * 2];
    acc[2 * cc] = db.x; acc[2 * cc + 1] = db.y;
  }
#define RECON_TERM(r)                                                          \
  {                                                                            \
    int f = seli[r]; float v = selv[r];                                        \
    const unsigned short* wd = WdecBf + (size_t)f * ND;                        \
    _Pragma("unroll")                                                          \
    for (int cc = 0; cc < 6; ++cc) {                                           \
      unsigned pr = *(const unsigned*)&wd[cc * 128 + lane * 2];                \
      acc[2 * cc] = fmaf(v, bfbits2f(pr & 0xFFFFu), acc[2 * cc]);              \
      acc[2 * cc + 1] = fmaf(v, bfbits2f(pr >> 16), acc[2 * cc + 1]);          \
    }                                                                          \
  }
  if (k == 32) {
#pragma unroll
    for (int r = 0; r < 32; ++r) RECON_TERM(r)
  } else {
    for (int r = 0; r < k; ++r) RECON_TERM(r)
  }
#pragma unroll
  for (int cc = 0; cc < 6; ++cc) {
    f32x2 st = {acc[2 * cc], acc[2 * cc + 1]};
    __builtin_nontemporal_store(st, (f32x2*)&out_rec[(size_t)b * ND + cc * 128 + lane * 2]);
  }
}

// ---------------------------------------------------------------------------
__global__ __launch_bounds__(256) void d2_sparse_k(
    const float* __restrict__ g_vals, const int* __restrict__ g_idxs,
    const int* __restrict__ kptr, float* __restrict__ out_sc) {
  const int b = blockIdx.x, tid = threadIdx.x;
  int k = *kptr; k = k < 1 ? 1 : (k > 64 ? 64 : k);
  __shared__ float row[NF];
  __shared__ float sv[64];
  __shared__ int si[64];
  if (tid < k) { sv[tid] = g_vals[(size_t)b * 64 + tid]; si[tid] = g_idxs[(size_t)b * 64 + tid]; }
  float4* r4 = (float4*)row;
#pragma unroll
  for (int i = 0; i < 8; ++i) r4[tid + 256 * i] = make_float4(0.f, 0.f, 0.f, 0.f);
  __syncthreads();
  if (tid < k) row[si[tid]] = sv[tid];
  __syncthreads();
  f32x4* o4 = (f32x4*)(out_sc + (size_t)b * NF);
  const f32x4* r4v = (const f32x4*)row;
#pragma unroll
  for (int i = 0; i < 8; ++i)
    __builtin_nontemporal_store(r4v[tid + 256 * i], &o4[tid + 256 * i]);
}

// ---------------------------------------------------------------------------
extern "C" void kernel_launch(void* const* d_in, const int* in_sizes, int n_in,
                              void* d_out, int out_size, void* d_ws, size_t ws_size,
                              hipStream_t stream) {
  const float* x        = (const float*)d_in[0];
  const float* W_enc    = (const float*)d_in[1];
  const float* b_enc    = (const float*)d_in[2];
  const float* W_dec    = (const float*)d_in[3];
  const float* dec_bias = (const float*)d_in[4];
  const int*   kptr     = (const int*)d_in[5];

  float* out_rec = (float*)d_out;
  float* out_sc  = (float*)d_out + (size_t)NB * ND;

  // scratch carved from the sparse-code output region (rewritten by d2 last)
  char* scb = (char*)out_sc;
  unsigned*       glist = (unsigned*)scb;                      // 64 MB
  unsigned short* Xbf   = (unsigned short*)(scb + 67108864);   // 24 MB
  unsigned short* Wbf   = (unsigned short*)(scb + 92274688);   // 12 MB

  char* ws = (char*)d_ws;
  unsigned short* WdecBf = (unsigned short*)ws;        // 12,582,912 B
  float* beta   = (float*)(ws + 12582912);             //     32,768 B
  float* g_vals = (float*)(ws + 12615680);             //  4,194,304 B
  int*   g_idxs = (int*)(ws + 16809984);               //  4,194,304 B

  cvt_bf16_k<<<(NB * ND) / 2048, 256, 0, stream>>>(x, Xbf);
  cvt_bf16_k<<<(NF * ND) / 2048, 256, 0, stream>>>(W_enc, Wbf);
  beta_k<<<NF / 4, 256, 0, stream>>>(W_enc, b_enc, dec_bias, beta);
  transpose_bf_k<<<dim3(NF / 32, ND / 32), 256, 0, stream>>>(W_dec, WdecBf);
  enc_gemm_bf16<<<dim3(NF / 128, NB / 128), 256, 0, stream>>>(Xbf, Wbf, beta, glist);
  ksel_k<<<NB / 4, 256, 0, stream>>>(glist, x, W_enc, beta, WdecBf, dec_bias, kptr,
                                     out_rec, g_vals, g_idxs);
  d2_sparse_k<<<NB, 256, 0, stream>>>(g_vals, g_idxs, kptr, out_sc);
}